// Round 1
// baseline (599.725 us; speedup 1.0000x reference)
//
#include <hip/hip_runtime.h>
#include <cstdint>

#define BB 2
#define NN 2048
#define DD 1024
#define HH 16
#define HD 64
#define HID_ 4096
#define MM (BB*NN)

typedef __bf16 bf16x8 __attribute__((ext_vector_type(8)));
typedef float  f32x4  __attribute__((ext_vector_type(4)));

__device__ inline void gload_lds16(const void* g, void* l) {
  __builtin_amdgcn_global_load_lds((const __attribute__((address_space(1))) char*)g,
                                   (__attribute__((address_space(3))) char*)l, 16, 0, 0);
}

// ---------- prep: combined decomposition kernel (softmax(alpha)-weighted) ----------
__global__ void k_wcomb(const float* __restrict__ alpha, const float* __restrict__ dw7,
                        const float* __restrict__ dw25, const float* __restrict__ dw49,
                        float* __restrict__ wc) {
  int t = blockIdx.x;  // 0..48
  float a0 = alpha[0], a1 = alpha[1], a2 = alpha[2];
  float mx = fmaxf(a0, fmaxf(a1, a2));
  float e0 = __expf(a0 - mx), e1 = __expf(a1 - mx), e2 = __expf(a2 - mx);
  float inv = 1.f / (e0 + e1 + e2);
  float w0 = e0 * inv, w1 = e1 * inv, w2 = e2 * inv;
  for (int d = threadIdx.x; d < DD; d += blockDim.x) {
    float v = w2 * dw49[d * 49 + t];
    if (t >= 12 && t <= 36) v += w1 * dw25[d * 25 + (t - 12)];
    if (t >= 21 && t <= 27) v += w0 * dw7[d * 7 + (t - 21)];
    wc[t * DD + d] = v;
  }
}

__global__ void k_bias3(const float* __restrict__ bq, const float* __restrict__ bk,
                        const float* __restrict__ bv, float* __restrict__ b3) {
  for (int i = threadIdx.x; i < 3 * DD; i += blockDim.x) {
    const float* s = (i < DD) ? bq : (i < 2 * DD ? bk : bv);
    b3[i] = s[i & (DD - 1)];
  }
}

__global__ void k_cvt(const float* __restrict__ s, __bf16* __restrict__ d, int n) {
  int i = (blockIdx.x * blockDim.x + threadIdx.x) * 4;
  if (i < n) {
    float4 v = *(const float4*)&s[i];
    d[i] = (__bf16)v.x; d[i + 1] = (__bf16)v.y; d[i + 2] = (__bf16)v.z; d[i + 3] = (__bf16)v.w;
  }
}

// ---------- series decomposition: T = conv49_mix(x), S = x - T ----------
__global__ __launch_bounds__(256) void k_decomp(const float* __restrict__ x,
                                                const float* __restrict__ wc,
                                                float* __restrict__ T, float* __restrict__ S) {
  int bn = blockIdx.x;
  int b = bn >> 11, n = bn & (NN - 1);
  const float* xb = x + (size_t)b * NN * DD;
  int d0 = threadIdx.x;
  float acc[4] = {0.f, 0.f, 0.f, 0.f};
  for (int t = 0; t < 49; ++t) {
    int nn = n + t - 24;
    nn = (nn < 0) ? -nn : (nn > NN - 1 ? 2 * (NN - 1) - nn : nn);
    const float* xr = xb + (size_t)nn * DD;
    const float* wr = wc + t * DD;
#pragma unroll
    for (int i = 0; i < 4; ++i) acc[i] += wr[d0 + i * 256] * xr[d0 + i * 256];
  }
  size_t base = (size_t)bn * DD;
#pragma unroll
  for (int i = 0; i < 4; ++i) {
    float xv = xb[(size_t)n * DD + d0 + i * 256];
    T[base + d0 + i * 256] = acc[i];
    S[base + d0 + i * 256] = xv - acc[i];
  }
}

// ---------- trend conv k=5, zero pad ----------
__global__ __launch_bounds__(256) void k_tout(const float* __restrict__ T,
                                              const float* __restrict__ tw,
                                              const float* __restrict__ tb,
                                              float* __restrict__ tout) {
  int bn = blockIdx.x;
  int b = bn >> 11, n = bn & (NN - 1);
  const float* Tb = T + (size_t)b * NN * DD;
  int d0 = threadIdx.x;
  float acc[4];
#pragma unroll
  for (int i = 0; i < 4; ++i) acc[i] = tb[d0 + i * 256];
  for (int t = 0; t < 5; ++t) {
    int nn = n + t - 2;
    if (nn < 0 || nn >= NN) continue;
#pragma unroll
    for (int i = 0; i < 4; ++i)
      acc[i] += tw[(d0 + i * 256) * 5 + t] * Tb[(size_t)nn * DD + d0 + i * 256];
  }
#pragma unroll
  for (int i = 0; i < 4; ++i) tout[(size_t)bn * DD + d0 + i * 256] = acc[i];
}

// ---------- LayerNorm (fp32 in -> bf16 out) ----------
__global__ __launch_bounds__(256) void k_ln(const float* __restrict__ x,
                                            const float* __restrict__ g,
                                            const float* __restrict__ bt,
                                            __bf16* __restrict__ y) {
  int row = blockIdx.x;
  const float* xr = x + (size_t)row * DD;
  int i = threadIdx.x * 4;
  float4 v = *(const float4*)&xr[i];
  float s = v.x + v.y + v.z + v.w;
  float sq = v.x * v.x + v.y * v.y + v.z * v.z + v.w * v.w;
#pragma unroll
  for (int m = 1; m <= 32; m <<= 1) { s += __shfl_xor(s, m); sq += __shfl_xor(sq, m); }
  __shared__ float rs[4], rq[4];
  int wid = threadIdx.x >> 6;
  if ((threadIdx.x & 63) == 0) { rs[wid] = s; rq[wid] = sq; }
  __syncthreads();
  s = rs[0] + rs[1] + rs[2] + rs[3];
  sq = rq[0] + rq[1] + rq[2] + rq[3];
  float mean = s * (1.f / DD);
  float var = sq * (1.f / DD) - mean * mean;
  float rstd = rsqrtf(var + 1e-5f);
  float4 gv = *(const float4*)&g[i];
  float4 bv = *(const float4*)&bt[i];
  __bf16* yr = y + (size_t)row * DD + i;
  yr[0] = (__bf16)((v.x - mean) * rstd * gv.x + bv.x);
  yr[1] = (__bf16)((v.y - mean) * rstd * gv.y + bv.y);
  yr[2] = (__bf16)((v.z - mean) * rstd * gv.z + bv.z);
  yr[3] = (__bf16)((v.w - mean) * rstd * gv.w + bv.w);
}

// ---------- GEMM: C[M,N] = A[M,K] * Bw[N,K]^T, templated epilogue ----------
// EPI 0: QKV permute+bias -> outb (3 x (B,H,N,64) bf16)
// EPI 1: O-proj: outf = aux1 + (val+bias)        (x_s = S + y), fp32
// EPI 2: FFN1: outb = bf16(gelu(val+bias))
// EPI 3: FFN2: outf = (val+bias) + aux1 + aux2   (final out), fp32
template <int EPI>
__global__ __launch_bounds__(256) void k_gemm(const __bf16* __restrict__ A,
                                              const __bf16* __restrict__ Bw, int K,
                                              const float* __restrict__ bias,
                                              const float* __restrict__ aux1,
                                              const float* __restrict__ aux2,
                                              float* __restrict__ outf,
                                              __bf16* __restrict__ outb) {
  __shared__ __bf16 aS[2][128 * 32];
  __shared__ __bf16 bS[2][128 * 32];
  const int tid = threadIdx.x;
  const int lane = tid & 63;
  const int wid = tid >> 6;
  const int wm = wid >> 1, wn = wid & 1;
  const int r = lane & 15, gq = lane >> 4;
  const int m0 = blockIdx.y * 128;
  const int n0 = blockIdx.x * 128;

  f32x4 acc[4][4];
#pragma unroll
  for (int mi = 0; mi < 4; ++mi)
#pragma unroll
    for (int ni = 0; ni < 4; ++ni) acc[mi][ni] = (f32x4){0.f, 0.f, 0.f, 0.f};

  auto stage = [&](int bufi, int k0) {
#pragma unroll
    for (int i = 0; i < 2; ++i) {
      int e = i * 2048 + tid * 8;
      int row = e >> 5, col = e & 31;
      gload_lds16(A + (size_t)(m0 + row) * K + k0 + col, &aS[bufi][e]);
      gload_lds16(Bw + (size_t)(n0 + row) * K + k0 + col, &bS[bufi][e]);
    }
  };

  stage(0, 0);
  const int nk = K >> 5;
  int buf = 0;
  for (int kt = 0; kt < nk; ++kt) {
    __syncthreads();
    if (kt + 1 < nk) stage(buf ^ 1, (kt + 1) << 5);
    bf16x8 af[4], bfr[4];
#pragma unroll
    for (int mi = 0; mi < 4; ++mi)
      af[mi] = *reinterpret_cast<const bf16x8*>(&aS[buf][(wm * 64 + mi * 16 + r) * 32 + gq * 8]);
#pragma unroll
    for (int ni = 0; ni < 4; ++ni)
      bfr[ni] = *reinterpret_cast<const bf16x8*>(&bS[buf][(wn * 64 + ni * 16 + r) * 32 + gq * 8]);
#pragma unroll
    for (int mi = 0; mi < 4; ++mi)
#pragma unroll
      for (int ni = 0; ni < 4; ++ni)
        acc[mi][ni] = __builtin_amdgcn_mfma_f32_16x16x32_bf16(af[mi], bfr[ni], acc[mi][ni], 0, 0, 0);
    buf ^= 1;
  }

#pragma unroll
  for (int mi = 0; mi < 4; ++mi) {
#pragma unroll
    for (int ni = 0; ni < 4; ++ni) {
      int colg = n0 + wn * 64 + ni * 16 + r;
      float bcol = bias[colg];
#pragma unroll
      for (int rr = 0; rr < 4; ++rr) {
        int mg = m0 + wm * 64 + mi * 16 + gq * 4 + rr;
        float val = acc[mi][ni][rr] + bcol;
        if constexpr (EPI == 0) {
          int which = colg >> 10, e = colg & 1023;
          int h = e >> 6, d = e & 63;
          int b = mg >> 11, nq = mg & (NN - 1);
          outb[(size_t)which * (BB * HH * NN * HD) +
               ((size_t)(b * HH + h) * NN + nq) * HD + d] = (__bf16)val;
        } else if constexpr (EPI == 1) {
          size_t idx = (size_t)mg * DD + colg;
          outf[idx] = aux1[idx] + val;
        } else if constexpr (EPI == 2) {
          float gl = val * 0.5f * (1.f + erff(val * 0.70710678118f));
          outb[(size_t)mg * HID_ + colg] = (__bf16)gl;
        } else {
          size_t idx = (size_t)mg * DD + colg;
          outf[idx] = val + aux1[idx] + aux2[idx];
        }
      }
    }
  }
}

// ---------- flash attention: 1 wave per 16 q-rows ----------
__global__ __launch_bounds__(64) void k_attn(const __bf16* __restrict__ qb,
                                             const __bf16* __restrict__ kb,
                                             const __bf16* __restrict__ vb,
                                             const float* __restrict__ pb,
                                             __bf16* __restrict__ ob) {
  __shared__ __bf16 p_lds[16 * 32];
  __shared__ __bf16 v_lds[32 * 68];
  int blk = blockIdx.x;
  int qt = blk & 127;           // N/16 = 128 q-tiles
  int bh = blk >> 7;
  int h = bh & (HH - 1), b = bh >> 4;
  int lane = threadIdx.x;
  int r = lane & 15, g = lane >> 4;
  const __bf16* Q = qb + ((size_t)bh * NN + qt * 16) * HD;
  const __bf16* Kp = kb + (size_t)bh * NN * HD;
  const __bf16* Vp = vb + (size_t)bh * NN * HD;

  bf16x8 qf[2];
  qf[0] = *reinterpret_cast<const bf16x8*>(&Q[r * HD + g * 8]);
  qf[1] = *reinterpret_cast<const bf16x8*>(&Q[r * HD + 32 + g * 8]);

  float slope = exp2f(-0.5f * (float)(h + 1));
  float mrow[4], lrow[4];
  f32x4 oacc[4];
#pragma unroll
  for (int rr = 0; rr < 4; ++rr) { mrow[rr] = -1e30f; lrow[rr] = 0.f; }
#pragma unroll
  for (int t = 0; t < 4; ++t) oacc[t] = (f32x4){0.f, 0.f, 0.f, 0.f};
  int qrow_base = qt * 16;

  for (int ch = 0; ch < NN / 32; ++ch) {
    int kc0 = ch * 32;
    // QK^T: S[16 q][32 kc]
    f32x4 sacc[2];
    sacc[0] = (f32x4){0.f, 0.f, 0.f, 0.f};
    sacc[1] = (f32x4){0.f, 0.f, 0.f, 0.f};
#pragma unroll
    for (int s = 0; s < 2; ++s) {
      bf16x8 kf0 = *reinterpret_cast<const bf16x8*>(&Kp[(size_t)(kc0 + s * 16 + r) * HD + g * 8]);
      bf16x8 kf1 = *reinterpret_cast<const bf16x8*>(&Kp[(size_t)(kc0 + s * 16 + r) * HD + 32 + g * 8]);
      sacc[s] = __builtin_amdgcn_mfma_f32_16x16x32_bf16(qf[0], kf0, sacc[s], 0, 0, 0);
      sacc[s] = __builtin_amdgcn_mfma_f32_16x16x32_bf16(qf[1], kf1, sacc[s], 0, 0, 0);
    }
    // V tile global->regs (coalesced 16B)
    uint4 vt[4];
#pragma unroll
    for (int i = 0; i < 4; ++i) {
      int flat = i * 64 + lane;
      int kc = flat >> 3, cc = (flat & 7) * 8;
      vt[i] = *reinterpret_cast<const uint4*>(&Vp[(size_t)(kc0 + kc) * HD + cc]);
    }
    // bias + alibi + online softmax
    float pv[2][4];
#pragma unroll
    for (int s = 0; s < 2; ++s) {
      int kcg = kc0 + s * 16 + r;
#pragma unroll
      for (int rr = 0; rr < 4; ++rr) {
        int qg = qrow_base + g * 4 + rr;
        float dist = (kcg > qg) ? (float)(kcg - qg) : 0.f;
        pv[s][rr] = sacc[s][rr] * 0.125f - slope * dist + pb[(size_t)qg * NN + kcg];
      }
    }
#pragma unroll
    for (int rr = 0; rr < 4; ++rr) {
      float mx = fmaxf(pv[0][rr], pv[1][rr]);
#pragma unroll
      for (int msk = 1; msk <= 8; msk <<= 1) mx = fmaxf(mx, __shfl_xor(mx, msk));
      float mnew = fmaxf(mrow[rr], mx);
      float sc = __expf(mrow[rr] - mnew);
      mrow[rr] = mnew;
      float p0 = __expf(pv[0][rr] - mnew), p1 = __expf(pv[1][rr] - mnew);
      pv[0][rr] = p0; pv[1][rr] = p1;
      float ps = p0 + p1;
#pragma unroll
      for (int msk = 1; msk <= 8; msk <<= 1) ps += __shfl_xor(ps, msk);
      lrow[rr] = lrow[rr] * sc + ps;
#pragma unroll
      for (int t = 0; t < 4; ++t) oacc[t][rr] *= sc;
    }
    // P -> LDS (C/D layout -> A layout bounce)
#pragma unroll
    for (int s = 0; s < 2; ++s)
#pragma unroll
      for (int rr = 0; rr < 4; ++rr)
        p_lds[(g * 4 + rr) * 32 + s * 16 + r] = (__bf16)pv[s][rr];
    // V regs -> LDS (padded stride 68 -> 2-way banks on strided reads)
#pragma unroll
    for (int i = 0; i < 4; ++i) {
      int flat = i * 64 + lane;
      int kc = flat >> 3, cc = (flat & 7) * 8;
      *reinterpret_cast<uint2*>(&v_lds[kc * 68 + cc]) = make_uint2(vt[i].x, vt[i].y);
      *reinterpret_cast<uint2*>(&v_lds[kc * 68 + cc + 4]) = make_uint2(vt[i].z, vt[i].w);
    }
    bf16x8 pa = *reinterpret_cast<const bf16x8*>(&p_lds[r * 32 + g * 8]);
#pragma unroll
    for (int t = 0; t < 4; ++t) {
      bf16x8 vf;
#pragma unroll
      for (int j = 0; j < 8; ++j) vf[j] = v_lds[(g * 8 + j) * 68 + t * 16 + r];
      oacc[t] = __builtin_amdgcn_mfma_f32_16x16x32_bf16(pa, vf, oacc[t], 0, 0, 0);
    }
  }
  // normalize + write o (B,N,H*64)
#pragma unroll
  for (int t = 0; t < 4; ++t) {
#pragma unroll
    for (int rr = 0; rr < 4; ++rr) {
      int qg = qrow_base + g * 4 + rr;
      float v = oacc[t][rr] / lrow[rr];
      ob[((size_t)(b * NN) + qg) * DD + h * HD + t * 16 + r] = (__bf16)v;
    }
  }
}

__global__ void k_tail(float* __restrict__ out) { out[(size_t)BB * NN * DD] = 0.f; }

extern "C" void kernel_launch(void* const* d_in, const int* in_sizes, int n_in,
                              void* d_out, int out_size, void* d_ws, size_t ws_size,
                              hipStream_t stream) {
  const float* x    = (const float*)d_in[0];
  const float* pb   = (const float*)d_in[1];
  const float* alpha= (const float*)d_in[2];
  const float* dw7  = (const float*)d_in[3];
  const float* dw25 = (const float*)d_in[4];
  const float* dw49 = (const float*)d_in[5];
  const float* ln1g = (const float*)d_in[6];
  const float* ln1b = (const float*)d_in[7];
  const float* ln2g = (const float*)d_in[8];
  const float* ln2b = (const float*)d_in[9];
  const float* Wq   = (const float*)d_in[10];
  const float* bq   = (const float*)d_in[11];
  const float* Wk   = (const float*)d_in[12];
  const float* bk   = (const float*)d_in[13];
  const float* Wv   = (const float*)d_in[14];
  const float* bv   = (const float*)d_in[15];
  const float* Wo   = (const float*)d_in[16];
  const float* bo   = (const float*)d_in[17];
  const float* W1   = (const float*)d_in[18];
  const float* b1   = (const float*)d_in[19];
  const float* W2   = (const float*)d_in[20];
  const float* b2   = (const float*)d_in[21];
  const float* tw   = (const float*)d_in[22];
  const float* tb   = (const float*)d_in[23];
  float* out = (float*)d_out;

  char* w = (char*)d_ws;
  size_t off = 0;
  auto alloc = [&](size_t bytes) -> char* {
    char* p = w + off;
    off = (off + bytes + 255) & ~(size_t)255;
    return p;
  };
  float*  wc    = (float*)alloc(49 * 1024 * 4);
  float*  b3    = (float*)alloc(3072 * 4);
  float*  Tbuf  = (float*)alloc((size_t)MM * DD * 4);
  float*  Sbuf  = (float*)alloc((size_t)MM * DD * 4);
  float*  toutb = (float*)alloc((size_t)MM * DD * 4);
  __bf16* sn    = (__bf16*)alloc((size_t)MM * DD * 2);
  __bf16* qkv   = (__bf16*)alloc((size_t)3 * MM * DD * 2);
  __bf16* gb    = (__bf16*)alloc((size_t)MM * HID_ * 2);
  __bf16* wqkvb = (__bf16*)alloc((size_t)3 * DD * DD * 2);
  __bf16* wob   = (__bf16*)alloc((size_t)DD * DD * 2);
  __bf16* w1b   = (__bf16*)alloc((size_t)HID_ * DD * 2);
  __bf16* w2b   = (__bf16*)alloc((size_t)DD * HID_ * 2);
  float*  xs    = Tbuf;   // alias: T dead after k_tout
  __bf16* obuf  = sn;     // alias: sn dead after QKV gemm
  __bf16* hb    = qkv;    // alias: q dead after attention

  k_wcomb<<<49, 256, 0, stream>>>(alpha, dw7, dw25, dw49, wc);
  k_bias3<<<1, 256, 0, stream>>>(bq, bk, bv, b3);
  k_cvt<<<1024, 256, 0, stream>>>(Wq, wqkvb, DD * DD);
  k_cvt<<<1024, 256, 0, stream>>>(Wk, wqkvb + DD * DD, DD * DD);
  k_cvt<<<1024, 256, 0, stream>>>(Wv, wqkvb + 2 * DD * DD, DD * DD);
  k_cvt<<<1024, 256, 0, stream>>>(Wo, wob, DD * DD);
  k_cvt<<<4096, 256, 0, stream>>>(W1, w1b, HID_ * DD);
  k_cvt<<<4096, 256, 0, stream>>>(W2, w2b, DD * HID_);
  k_decomp<<<MM, 256, 0, stream>>>(x, wc, Tbuf, Sbuf);
  k_tout<<<MM, 256, 0, stream>>>(Tbuf, tw, tb, toutb);
  k_ln<<<MM, 256, 0, stream>>>(Sbuf, ln1g, ln1b, sn);
  k_gemm<0><<<dim3(24, 32), 256, 0, stream>>>(sn, wqkvb, DD, b3, nullptr, nullptr, nullptr, qkv);
  k_attn<<<BB * HH * (NN / 16), 64, 0, stream>>>(qkv, qkv + (size_t)BB * HH * NN * HD,
                                                 qkv + (size_t)2 * BB * HH * NN * HD, pb, obuf);
  k_gemm<1><<<dim3(8, 32), 256, 0, stream>>>(obuf, wob, DD, bo, Sbuf, nullptr, xs, nullptr);
  k_ln<<<MM, 256, 0, stream>>>(xs, ln2g, ln2b, hb);
  k_gemm<2><<<dim3(32, 32), 256, 0, stream>>>(hb, w1b, DD, b1, nullptr, nullptr, nullptr, gb);
  k_gemm<3><<<dim3(8, 32), 256, 0, stream>>>(gb, w2b, HID_, b2, xs, toutb, out, nullptr);
  k_tail<<<1, 1, 0, stream>>>(out);
}

// Round 2
// 502.641 us; speedup vs baseline: 1.1931x; 1.1931x over previous
//
#include <hip/hip_runtime.h>
#include <cstdint>

#define BB 2
#define NN 2048
#define DD 1024
#define HH 16
#define HD 64
#define HID_ 4096
#define MM (BB*NN)

typedef __bf16 bf16x8 __attribute__((ext_vector_type(8)));
typedef float  f32x4  __attribute__((ext_vector_type(4)));

__device__ inline void gload_lds16(const void* g, void* l) {
  __builtin_amdgcn_global_load_lds((const __attribute__((address_space(1))) char*)g,
                                   (__attribute__((address_space(3))) char*)l, 16, 0, 0);
}

// ---------- prep: combined decomposition kernel (softmax(alpha)-weighted) ----------
__global__ void k_wcomb(const float* __restrict__ alpha, const float* __restrict__ dw7,
                        const float* __restrict__ dw25, const float* __restrict__ dw49,
                        float* __restrict__ wc) {
  int t = blockIdx.x;  // 0..48
  float a0 = alpha[0], a1 = alpha[1], a2 = alpha[2];
  float mx = fmaxf(a0, fmaxf(a1, a2));
  float e0 = __expf(a0 - mx), e1 = __expf(a1 - mx), e2 = __expf(a2 - mx);
  float inv = 1.f / (e0 + e1 + e2);
  float w0 = e0 * inv, w1 = e1 * inv, w2 = e2 * inv;
  for (int d = threadIdx.x; d < DD; d += blockDim.x) {
    float v = w2 * dw49[d * 49 + t];
    if (t >= 12 && t <= 36) v += w1 * dw25[d * 25 + (t - 12)];
    if (t >= 21 && t <= 27) v += w0 * dw7[d * 7 + (t - 21)];
    wc[t * DD + d] = v;
  }
}

__global__ void k_bias3(const float* __restrict__ bq, const float* __restrict__ bk,
                        const float* __restrict__ bv, float* __restrict__ b3) {
  for (int i = threadIdx.x; i < 3 * DD; i += blockDim.x) {
    const float* s = (i < DD) ? bq : (i < 2 * DD ? bk : bv);
    b3[i] = s[i & (DD - 1)];
  }
}

__global__ void k_cvt(const float* __restrict__ s, __bf16* __restrict__ d, int n) {
  int i = (blockIdx.x * blockDim.x + threadIdx.x) * 4;
  if (i < n) {
    float4 v = *(const float4*)&s[i];
    d[i] = (__bf16)v.x; d[i + 1] = (__bf16)v.y; d[i + 2] = (__bf16)v.z; d[i + 3] = (__bf16)v.w;
  }
}

// pb -> bf16 in MFMA-fragment tiles: tile (q16,k16), elem (qm,km) at (qm>>2)*64 + km*4 + (qm&3)
__global__ __launch_bounds__(256) void k_pbt(const float* __restrict__ pb,
                                             __bf16* __restrict__ pbt) {
  int q = blockIdx.x;
  int qt = q >> 4, qm = q & 15;
  int base_q = (qm >> 2) * 64 + (qm & 3);
  for (int k = threadIdx.x; k < NN; k += 256) {
    float v = pb[(size_t)q * NN + k];
    pbt[((size_t)qt * 128 + (k >> 4)) * 256 + base_q + (k & 15) * 4] = (__bf16)v;
  }
}

// ---------- series decomposition: T = conv49_mix(x), S = x - T ----------
__global__ __launch_bounds__(256) void k_decomp(const float* __restrict__ x,
                                                const float* __restrict__ wc,
                                                float* __restrict__ T, float* __restrict__ S) {
  int bn = blockIdx.x;
  int b = bn >> 11, n = bn & (NN - 1);
  const float* xb = x + (size_t)b * NN * DD;
  int d0 = threadIdx.x;
  float acc[4] = {0.f, 0.f, 0.f, 0.f};
  for (int t = 0; t < 49; ++t) {
    int nn = n + t - 24;
    nn = (nn < 0) ? -nn : (nn > NN - 1 ? 2 * (NN - 1) - nn : nn);
    const float* xr = xb + (size_t)nn * DD;
    const float* wr = wc + t * DD;
#pragma unroll
    for (int i = 0; i < 4; ++i) acc[i] += wr[d0 + i * 256] * xr[d0 + i * 256];
  }
  size_t base = (size_t)bn * DD;
#pragma unroll
  for (int i = 0; i < 4; ++i) {
    float xv = xb[(size_t)n * DD + d0 + i * 256];
    T[base + d0 + i * 256] = acc[i];
    S[base + d0 + i * 256] = xv - acc[i];
  }
}

// ---------- trend conv k=5, zero pad ----------
__global__ __launch_bounds__(256) void k_tout(const float* __restrict__ T,
                                              const float* __restrict__ tw,
                                              const float* __restrict__ tb,
                                              float* __restrict__ tout) {
  int bn = blockIdx.x;
  int b = bn >> 11, n = bn & (NN - 1);
  const float* Tb = T + (size_t)b * NN * DD;
  int d0 = threadIdx.x;
  float acc[4];
#pragma unroll
  for (int i = 0; i < 4; ++i) acc[i] = tb[d0 + i * 256];
  for (int t = 0; t < 5; ++t) {
    int nn = n + t - 2;
    if (nn < 0 || nn >= NN) continue;
#pragma unroll
    for (int i = 0; i < 4; ++i)
      acc[i] += tw[(d0 + i * 256) * 5 + t] * Tb[(size_t)nn * DD + d0 + i * 256];
  }
#pragma unroll
  for (int i = 0; i < 4; ++i) tout[(size_t)bn * DD + d0 + i * 256] = acc[i];
}

// ---------- LayerNorm (fp32 in -> bf16 out) ----------
__global__ __launch_bounds__(256) void k_ln(const float* __restrict__ x,
                                            const float* __restrict__ g,
                                            const float* __restrict__ bt,
                                            __bf16* __restrict__ y) {
  int row = blockIdx.x;
  const float* xr = x + (size_t)row * DD;
  int i = threadIdx.x * 4;
  float4 v = *(const float4*)&xr[i];
  float s = v.x + v.y + v.z + v.w;
  float sq = v.x * v.x + v.y * v.y + v.z * v.z + v.w * v.w;
#pragma unroll
  for (int m = 1; m <= 32; m <<= 1) { s += __shfl_xor(s, m); sq += __shfl_xor(sq, m); }
  __shared__ float rs[4], rq[4];
  int wid = threadIdx.x >> 6;
  if ((threadIdx.x & 63) == 0) { rs[wid] = s; rq[wid] = sq; }
  __syncthreads();
  s = rs[0] + rs[1] + rs[2] + rs[3];
  sq = rq[0] + rq[1] + rq[2] + rq[3];
  float mean = s * (1.f / DD);
  float var = sq * (1.f / DD) - mean * mean;
  float rstd = rsqrtf(var + 1e-5f);
  float4 gv = *(const float4*)&g[i];
  float4 bv = *(const float4*)&bt[i];
  __bf16* yr = y + (size_t)row * DD + i;
  yr[0] = (__bf16)((v.x - mean) * rstd * gv.x + bv.x);
  yr[1] = (__bf16)((v.y - mean) * rstd * gv.y + bv.y);
  yr[2] = (__bf16)((v.z - mean) * rstd * gv.z + bv.z);
  yr[3] = (__bf16)((v.w - mean) * rstd * gv.w + bv.w);
}

// ---------- GEMM: C[M,N] = A[M,K] * Bw[N,K]^T, templated epilogue ----------
template <int EPI>
__global__ __launch_bounds__(256) void k_gemm(const __bf16* __restrict__ A,
                                              const __bf16* __restrict__ Bw, int K,
                                              const float* __restrict__ bias,
                                              const float* __restrict__ aux1,
                                              const float* __restrict__ aux2,
                                              float* __restrict__ outf,
                                              __bf16* __restrict__ outb) {
  __shared__ __bf16 aS[2][128 * 32];
  __shared__ __bf16 bS[2][128 * 32];
  const int tid = threadIdx.x;
  const int lane = tid & 63;
  const int wid = tid >> 6;
  const int wm = wid >> 1, wn = wid & 1;
  const int r = lane & 15, gq = lane >> 4;
  const int m0 = blockIdx.y * 128;
  const int n0 = blockIdx.x * 128;

  f32x4 acc[4][4];
#pragma unroll
  for (int mi = 0; mi < 4; ++mi)
#pragma unroll
    for (int ni = 0; ni < 4; ++ni) acc[mi][ni] = (f32x4){0.f, 0.f, 0.f, 0.f};

  auto stage = [&](int bufi, int k0) {
#pragma unroll
    for (int i = 0; i < 2; ++i) {
      int e = i * 2048 + tid * 8;
      int row = e >> 5, col = e & 31;
      gload_lds16(A + (size_t)(m0 + row) * K + k0 + col, &aS[bufi][e]);
      gload_lds16(Bw + (size_t)(n0 + row) * K + k0 + col, &bS[bufi][e]);
    }
  };

  stage(0, 0);
  const int nk = K >> 5;
  int buf = 0;
  for (int kt = 0; kt < nk; ++kt) {
    __syncthreads();
    if (kt + 1 < nk) stage(buf ^ 1, (kt + 1) << 5);
    bf16x8 af[4], bfr[4];
#pragma unroll
    for (int mi = 0; mi < 4; ++mi)
      af[mi] = *reinterpret_cast<const bf16x8*>(&aS[buf][(wm * 64 + mi * 16 + r) * 32 + gq * 8]);
#pragma unroll
    for (int ni = 0; ni < 4; ++ni)
      bfr[ni] = *reinterpret_cast<const bf16x8*>(&bS[buf][(wn * 64 + ni * 16 + r) * 32 + gq * 8]);
#pragma unroll
    for (int mi = 0; mi < 4; ++mi)
#pragma unroll
      for (int ni = 0; ni < 4; ++ni)
        acc[mi][ni] = __builtin_amdgcn_mfma_f32_16x16x32_bf16(af[mi], bfr[ni], acc[mi][ni], 0, 0, 0);
    buf ^= 1;
  }

#pragma unroll
  for (int mi = 0; mi < 4; ++mi) {
#pragma unroll
    for (int ni = 0; ni < 4; ++ni) {
      int colg = n0 + wn * 64 + ni * 16 + r;
      float bcol = bias[colg];
#pragma unroll
      for (int rr = 0; rr < 4; ++rr) {
        int mg = m0 + wm * 64 + mi * 16 + gq * 4 + rr;
        float val = acc[mi][ni][rr] + bcol;
        if constexpr (EPI == 0) {
          int which = colg >> 10, e = colg & 1023;
          int hh = e >> 6, d = e & 63;
          int b = mg >> 11, nq = mg & (NN - 1);
          if (which == 2)  // V stored transposed: (b,h,d,n)
            outb[(size_t)2 * (BB * HH * NN * HD) +
                 ((size_t)((b * HH + hh) * HD + d)) * NN + nq] = (__bf16)val;
          else
            outb[(size_t)which * (BB * HH * NN * HD) +
                 ((size_t)(b * HH + hh) * NN + nq) * HD + d] = (__bf16)val;
        } else if constexpr (EPI == 1) {
          size_t idx = (size_t)mg * DD + colg;
          outf[idx] = aux1[idx] + val;
        } else if constexpr (EPI == 2) {
          float gl = val * 0.5f * (1.f + erff(val * 0.70710678118f));
          outb[(size_t)mg * HID_ + colg] = (__bf16)gl;
        } else {
          size_t idx = (size_t)mg * DD + colg;
          outf[idx] = val + aux1[idx] + aux2[idx];
        }
      }
    }
  }
}

// ---------- flash attention v2: 4 waves/block, 64q x 64k tiles, LDS-staged K/V^T ----------
__global__ __launch_bounds__(256) void k_attn(const __bf16* __restrict__ qb,
                                              const __bf16* __restrict__ kb,
                                              const __bf16* __restrict__ vtb,
                                              const __bf16* __restrict__ pbt,
                                              __bf16* __restrict__ ob) {
  __shared__ __bf16 kS[2][64 * 64];
  __shared__ __bf16 vS[2][64 * 64];
  __shared__ __bf16 pS[4][16 * 72];
  int blk = blockIdx.x;
  int qt = blk & 31, bh = blk >> 5;
  int h = bh & (HH - 1), b = bh >> 4;
  int tid = threadIdx.x;
  int lane = tid & 63, w = tid >> 6;
  int r = lane & 15, g = lane >> 4;
  const __bf16* Kp = kb + (size_t)bh * NN * HD;
  const __bf16* Vt = vtb + (size_t)bh * HD * NN;
  int qbase = qt * 64 + w * 16;
  const __bf16* Q = qb + ((size_t)bh * NN + qbase) * HD;
  __bf16* pw = &pS[w][0];

  bf16x8 qf0 = *(const bf16x8*)&Q[(size_t)r * HD + g * 8];
  bf16x8 qf1 = *(const bf16x8*)&Q[(size_t)r * HD + 32 + g * 8];
  bf16x8 onesf;
#pragma unroll
  for (int j = 0; j < 8; ++j) onesf[j] = (__bf16)1.0f;

  float slope = exp2f(-0.5f * (float)(h + 1));
  float mrow[4];
  f32x4 oacc[4], lacc;
#pragma unroll
  for (int rr = 0; rr < 4; ++rr) mrow[rr] = -1e30f;
#pragma unroll
  for (int t = 0; t < 4; ++t) oacc[t] = (f32x4){0.f, 0.f, 0.f, 0.f};
  lacc = (f32x4){0.f, 0.f, 0.f, 0.f};

  // stage K chunk + V^T chunk with pre-swizzled global source (LDS stays linear)
  auto stage = [&](int bufi, int kc0) {
#pragma unroll
    for (int i = 0; i < 2; ++i) {
      int idx = i * 256 + tid;            // 0..511
      int row = idx >> 3;                 // 0..63
      int c = (idx & 7) * 8;
      int src = c ^ ((row & 7) * 8);
      gload_lds16(Kp + (size_t)(kc0 + row) * HD + src, &kS[bufi][idx * 8]);
    }
#pragma unroll
    for (int i = 0; i < 2; ++i) {
      int idx = i * 256 + tid;
      int row = idx >> 3;                 // d
      int c = (idx & 7) * 8;
      int src = c ^ ((row & 7) * 8);
      gload_lds16(Vt + (size_t)row * NN + kc0 + src, &vS[bufi][idx * 8]);
    }
  };

  stage(0, 0);
  int buf = 0;
  int qtile128 = (qt * 4 + w) * 128;
  int sw = (r & 7) * 8;

  for (int ch = 0; ch < NN / 64; ++ch) {
    int kc0 = ch * 64;
    __syncthreads();
    if (ch + 1 < NN / 64) stage(buf ^ 1, kc0 + 64);

    // periodic bias: one 8B coalesced load per 16-k subtile
    float pbv[4][4];
#pragma unroll
    for (int st = 0; st < 4; ++st) {
      uint2 u = *(const uint2*)&pbt[((size_t)(qtile128 + (kc0 >> 4) + st)) * 256 + g * 64 + r * 4];
      pbv[st][0] = __uint_as_float(u.x << 16);
      pbv[st][1] = __uint_as_float(u.x & 0xffff0000u);
      pbv[st][2] = __uint_as_float(u.y << 16);
      pbv[st][3] = __uint_as_float(u.y & 0xffff0000u);
    }

    // QK^T: S[16q][64k]
    f32x4 sacc[4];
#pragma unroll
    for (int st = 0; st < 4; ++st) {
      sacc[st] = (f32x4){0.f, 0.f, 0.f, 0.f};
      int rowb = (st * 16 + r) * 64;
      bf16x8 kf0 = *(const bf16x8*)&kS[buf][rowb + ((g * 8) ^ sw)];
      bf16x8 kf1 = *(const bf16x8*)&kS[buf][rowb + ((32 + g * 8) ^ sw)];
      sacc[st] = __builtin_amdgcn_mfma_f32_16x16x32_bf16(qf0, kf0, sacc[st], 0, 0, 0);
      sacc[st] = __builtin_amdgcn_mfma_f32_16x16x32_bf16(qf1, kf1, sacc[st], 0, 0, 0);
    }

    // logits
    float pv[4][4];
#pragma unroll
    for (int st = 0; st < 4; ++st) {
      int kcg = kc0 + st * 16 + r;
#pragma unroll
      for (int rr = 0; rr < 4; ++rr) {
        int qg = qbase + g * 4 + rr;
        float dist = (kcg > qg) ? (float)(kcg - qg) : 0.f;
        pv[st][rr] = sacc[st][rr] * 0.125f - slope * dist + pbv[st][rr];
      }
    }

    // deferred online max (T13, THR=8)
    float pmax[4];
#pragma unroll
    for (int rr = 0; rr < 4; ++rr)
      pmax[rr] = fmaxf(fmaxf(pv[0][rr], pv[1][rr]), fmaxf(pv[2][rr], pv[3][rr]));
    int need = (pmax[0] > mrow[0] + 8.f) | (pmax[1] > mrow[1] + 8.f) |
               (pmax[2] > mrow[2] + 8.f) | (pmax[3] > mrow[3] + 8.f);
    if (__any(need)) {
#pragma unroll
      for (int rr = 0; rr < 4; ++rr) {
        float mx = pmax[rr];
#pragma unroll
        for (int msk = 1; msk <= 8; msk <<= 1) mx = fmaxf(mx, __shfl_xor(mx, msk));
        float mnew = fmaxf(mrow[rr], mx);
        float sc = __expf(mrow[rr] - mnew);
        mrow[rr] = mnew;
        lacc[rr] *= sc;
#pragma unroll
        for (int t = 0; t < 4; ++t) oacc[t][rr] *= sc;
      }
    }

    // exp + P -> per-wave LDS (padded stride 72)
#pragma unroll
    for (int st = 0; st < 4; ++st)
#pragma unroll
      for (int rr = 0; rr < 4; ++rr) {
        float p = __expf(pv[st][rr] - mrow[rr]);
        pw[(g * 4 + rr) * 72 + st * 16 + r] = (__bf16)p;
      }
    bf16x8 pa0 = *(const bf16x8*)&pw[r * 72 + g * 8];
    bf16x8 pa1 = *(const bf16x8*)&pw[r * 72 + 32 + g * 8];

    // PV + row-sum via ones-column MFMA
#pragma unroll
    for (int t = 0; t < 4; ++t) {
      int rowb = (t * 16 + r) * 64;
      bf16x8 vf0 = *(const bf16x8*)&vS[buf][rowb + ((g * 8) ^ sw)];
      bf16x8 vf1 = *(const bf16x8*)&vS[buf][rowb + ((32 + g * 8) ^ sw)];
      oacc[t] = __builtin_amdgcn_mfma_f32_16x16x32_bf16(pa0, vf0, oacc[t], 0, 0, 0);
      oacc[t] = __builtin_amdgcn_mfma_f32_16x16x32_bf16(pa1, vf1, oacc[t], 0, 0, 0);
    }
    lacc = __builtin_amdgcn_mfma_f32_16x16x32_bf16(pa0, onesf, lacc, 0, 0, 0);
    lacc = __builtin_amdgcn_mfma_f32_16x16x32_bf16(pa1, onesf, lacc, 0, 0, 0);
    buf ^= 1;
  }

  // normalize + write o (B,N,H*64)
#pragma unroll
  for (int rr = 0; rr < 4; ++rr) {
    int qg = qbase + g * 4 + rr;
    float inv = 1.f / lacc[rr];
#pragma unroll
    for (int t = 0; t < 4; ++t) {
      float v = oacc[t][rr] * inv;
      ob[((size_t)(b * NN) + qg) * DD + h * HD + t * 16 + r] = (__bf16)v;
    }
  }
}

__global__ void k_tail(float* __restrict__ out) { out[(size_t)BB * NN * DD] = 0.f; }

extern "C" void kernel_launch(void* const* d_in, const int* in_sizes, int n_in,
                              void* d_out, int out_size, void* d_ws, size_t ws_size,
                              hipStream_t stream) {
  const float* x    = (const float*)d_in[0];
  const float* pb   = (const float*)d_in[1];
  const float* alpha= (const float*)d_in[2];
  const float* dw7  = (const float*)d_in[3];
  const float* dw25 = (const float*)d_in[4];
  const float* dw49 = (const float*)d_in[5];
  const float* ln1g = (const float*)d_in[6];
  const float* ln1b = (const float*)d_in[7];
  const float* ln2g = (const float*)d_in[8];
  const float* ln2b = (const float*)d_in[9];
  const float* Wq   = (const float*)d_in[10];
  const float* bq   = (const float*)d_in[11];
  const float* Wk   = (const float*)d_in[12];
  const float* bk   = (const float*)d_in[13];
  const float* Wv   = (const float*)d_in[14];
  const float* bv   = (const float*)d_in[15];
  const float* Wo   = (const float*)d_in[16];
  const float* bo   = (const float*)d_in[17];
  const float* W1   = (const float*)d_in[18];
  const float* b1   = (const float*)d_in[19];
  const float* W2   = (const float*)d_in[20];
  const float* b2   = (const float*)d_in[21];
  const float* tw   = (const float*)d_in[22];
  const float* tb   = (const float*)d_in[23];
  float* out = (float*)d_out;

  char* w = (char*)d_ws;
  size_t off = 0;
  auto alloc = [&](size_t bytes) -> char* {
    char* p = w + off;
    off = (off + bytes + 255) & ~(size_t)255;
    return p;
  };
  float*  wc    = (float*)alloc(49 * 1024 * 4);
  float*  b3    = (float*)alloc(3072 * 4);
  float*  Tbuf  = (float*)alloc((size_t)MM * DD * 4);
  float*  Sbuf  = (float*)alloc((size_t)MM * DD * 4);
  float*  toutb = (float*)alloc((size_t)MM * DD * 4);
  __bf16* sn    = (__bf16*)alloc((size_t)MM * DD * 2);
  __bf16* qkv   = (__bf16*)alloc((size_t)3 * MM * DD * 2);
  __bf16* gb    = (__bf16*)alloc((size_t)MM * HID_ * 2);
  __bf16* wqkvb = (__bf16*)alloc((size_t)3 * DD * DD * 2);
  __bf16* wob   = (__bf16*)alloc((size_t)DD * DD * 2);
  __bf16* w1b   = (__bf16*)alloc((size_t)HID_ * DD * 2);
  __bf16* w2b   = (__bf16*)alloc((size_t)DD * HID_ * 2);
  __bf16* pbt   = (__bf16*)alloc((size_t)NN * NN * 2);
  float*  xs    = Tbuf;   // alias: T dead after k_tout
  __bf16* obuf  = sn;     // alias: sn dead after QKV gemm
  __bf16* hb    = qkv;    // alias: q dead after attention

  const size_t BHND = (size_t)BB * HH * NN * HD;

  k_wcomb<<<49, 256, 0, stream>>>(alpha, dw7, dw25, dw49, wc);
  k_bias3<<<1, 256, 0, stream>>>(bq, bk, bv, b3);
  k_pbt<<<NN, 256, 0, stream>>>(pb, pbt);
  k_cvt<<<1024, 256, 0, stream>>>(Wq, wqkvb, DD * DD);
  k_cvt<<<1024, 256, 0, stream>>>(Wk, wqkvb + DD * DD, DD * DD);
  k_cvt<<<1024, 256, 0, stream>>>(Wv, wqkvb + 2 * DD * DD, DD * DD);
  k_cvt<<<1024, 256, 0, stream>>>(Wo, wob, DD * DD);
  k_cvt<<<4096, 256, 0, stream>>>(W1, w1b, HID_ * DD);
  k_cvt<<<4096, 256, 0, stream>>>(W2, w2b, DD * HID_);
  k_decomp<<<MM, 256, 0, stream>>>(x, wc, Tbuf, Sbuf);
  k_tout<<<MM, 256, 0, stream>>>(Tbuf, tw, tb, toutb);
  k_ln<<<MM, 256, 0, stream>>>(Sbuf, ln1g, ln1b, sn);
  k_gemm<0><<<dim3(24, 32), 256, 0, stream>>>(sn, wqkvb, DD, b3, nullptr, nullptr, nullptr, qkv);
  k_attn<<<BB * HH * (NN / 64), 256, 0, stream>>>(qkv, qkv + BHND, qkv + 2 * BHND, pbt, obuf);
  k_gemm<1><<<dim3(8, 32), 256, 0, stream>>>(obuf, wob, DD, bo, Sbuf, nullptr, xs, nullptr);
  k_ln<<<MM, 256, 0, stream>>>(xs, ln2g, ln2b, hb);
  k_gemm<2><<<dim3(32, 32), 256, 0, stream>>>(hb, w1b, DD, b1, nullptr, nullptr, nullptr, gb);
  k_gemm<3><<<dim3(8, 32), 256, 0, stream>>>(gb, w2b, HID_, b2, xs, toutb, out, nullptr);
  k_tail<<<1, 1, 0, stream>>>(out);
}

// Round 4
// 386.271 us; speedup vs baseline: 1.5526x; 1.3013x over previous
//
#include <hip/hip_runtime.h>
#include <cstdint>

#define BB 2
#define NN 2048
#define DD 1024
#define HH 16
#define HD 64
#define HID_ 4096
#define MM (BB*NN)

typedef __bf16 bf16x8 __attribute__((ext_vector_type(8)));
typedef float  f32x4  __attribute__((ext_vector_type(4)));

__device__ inline void gload_lds16(const void* g, void* l) {
  __builtin_amdgcn_global_load_lds((const __attribute__((address_space(1))) char*)g,
                                   (__attribute__((address_space(3))) char*)l, 16, 0, 0);
}

// ---------- prep: combined decomposition weights ----------
__global__ void k_wcomb(const float* __restrict__ alpha, const float* __restrict__ dw7,
                        const float* __restrict__ dw25, const float* __restrict__ dw49,
                        float* __restrict__ wc) {
  int t = blockIdx.x;  // 0..48
  float a0 = alpha[0], a1 = alpha[1], a2 = alpha[2];
  float mx = fmaxf(a0, fmaxf(a1, a2));
  float e0 = __expf(a0 - mx), e1 = __expf(a1 - mx), e2 = __expf(a2 - mx);
  float inv = 1.f / (e0 + e1 + e2);
  float w0 = e0 * inv, w1 = e1 * inv, w2 = e2 * inv;
  for (int d = threadIdx.x; d < DD; d += blockDim.x) {
    float v = w2 * dw49[d * 49 + t];
    if (t >= 12 && t <= 36) v += w1 * dw25[d * 25 + (t - 12)];
    if (t >= 21 && t <= 27) v += w0 * dw7[d * 7 + (t - 21)];
    wc[t * DD + d] = v;
  }
}

__global__ void k_bias3(const float* __restrict__ bq, const float* __restrict__ bk,
                        const float* __restrict__ bv, float* __restrict__ b3) {
  for (int i = threadIdx.x; i < 3 * DD; i += blockDim.x) {
    const float* s = (i < DD) ? bq : (i < 2 * DD ? bk : bv);
    b3[i] = s[i & (DD - 1)];
  }
}

// all weight converts in one launch; dst = [qkv 3M][wo 1M][w1 4M][w2 4M]
__global__ __launch_bounds__(256) void k_cvtall(const float* __restrict__ Wq, const float* __restrict__ Wk,
                         const float* __restrict__ Wv, const float* __restrict__ Wo,
                         const float* __restrict__ W1, const float* __restrict__ W2,
                         __bf16* __restrict__ dst) {
  size_t i = ((size_t)blockIdx.x * 256 + threadIdx.x) * 4;
  const float* s;
  if (i < 1048576u) s = Wq + i;
  else if (i < 2097152u) s = Wk + (i - 1048576u);
  else if (i < 3145728u) s = Wv + (i - 2097152u);
  else if (i < 4194304u) s = Wo + (i - 3145728u);
  else if (i < 8388608u) s = W1 + (i - 4194304u);
  else s = W2 + (i - 8388608u);
  float4 v = *(const float4*)s;
  dst[i] = (__bf16)v.x; dst[i+1] = (__bf16)v.y; dst[i+2] = (__bf16)v.z; dst[i+3] = (__bf16)v.w;
}

// pb -> bf16*log2e, fragment-tiled for swapped-QK^T lane layout:
// element (q,k): tile (q>>4, k>>4), offset ((q&15) + 16*((k>>2)&3))*4 + (k&3)
__global__ __launch_bounds__(256) void k_pbt(const float* __restrict__ pb,
                                             __bf16* __restrict__ pbt) {
  int q = blockIdx.x;
  int qt16 = q >> 4, qm = q & 15;
  for (int k = threadIdx.x; k < NN; k += 256) {
    float v = pb[(size_t)q * NN + k] * 1.4426950408889634f;
    int kt = k >> 4, g = (k >> 2) & 3, rr = k & 3;
    pbt[((size_t)qt16 * 128 + kt) * 256 + (qm + 16 * g) * 4 + rr] = (__bf16)v;
  }
}

// ---------- series decomposition: register sliding window, 16-row strips ----------
__global__ __launch_bounds__(256) void k_decomp(const float* __restrict__ x,
                                                const float* __restrict__ wc,
                                                float* __restrict__ T, float* __restrict__ S) {
  int bid = blockIdx.x;
  int db = bid & 3, ns = (bid >> 2) & 127, b = bid >> 9;
  int d = db * 256 + threadIdx.x;
  const float* xb = x + (size_t)b * NN * DD + d;
  float xw[64];
#pragma unroll
  for (int i = 0; i < 64; ++i) {
    int n = ns * 16 - 24 + i;
    n = (n < 0) ? -n : n;
    n = (n > NN - 1) ? 2 * (NN - 1) - n : n;
    xw[i] = xb[(size_t)n * DD];
  }
  float acc[16];
#pragma unroll
  for (int i = 0; i < 16; ++i) acc[i] = 0.f;
#pragma unroll
  for (int t = 0; t < 49; ++t) {
    float wv = wc[t * DD + d];
#pragma unroll
    for (int i = 0; i < 16; ++i) acc[i] = fmaf(wv, xw[i + t], acc[i]);
  }
  size_t base = ((size_t)b * NN + ns * 16) * DD + d;
#pragma unroll
  for (int i = 0; i < 16; ++i) {
    T[base + (size_t)i * DD] = acc[i];
    S[base + (size_t)i * DD] = xw[i + 24] - acc[i];
  }
}

// ---------- trend conv k=5, zero pad: sliding window ----------
__global__ __launch_bounds__(256) void k_tout(const float* __restrict__ T,
                                              const float* __restrict__ tw,
                                              const float* __restrict__ tb,
                                              float* __restrict__ tout) {
  int bid = blockIdx.x;
  int db = bid & 3, ns = (bid >> 2) & 127, b = bid >> 9;
  int d = db * 256 + threadIdx.x;
  const float* Tb = T + (size_t)b * NN * DD + d;
  float xw[20];
#pragma unroll
  for (int i = 0; i < 20; ++i) {
    int n = ns * 16 - 2 + i;
    xw[i] = (n < 0 || n >= NN) ? 0.f : Tb[(size_t)n * DD];
  }
  float bv = tb[d];
  float acc[16];
#pragma unroll
  for (int i = 0; i < 16; ++i) acc[i] = bv;
#pragma unroll
  for (int t = 0; t < 5; ++t) {
    float wv = tw[d * 5 + t];
#pragma unroll
    for (int i = 0; i < 16; ++i) acc[i] = fmaf(wv, xw[i + t], acc[i]);
  }
  size_t base = ((size_t)b * NN + ns * 16) * DD + d;
#pragma unroll
  for (int i = 0; i < 16; ++i) tout[base + (size_t)i * DD] = acc[i];
}

// ---------- LayerNorm (fp32 in -> bf16 out) ----------
__global__ __launch_bounds__(256) void k_ln(const float* __restrict__ x,
                                            const float* __restrict__ g,
                                            const float* __restrict__ bt,
                                            __bf16* __restrict__ y) {
  int row = blockIdx.x;
  const float* xr = x + (size_t)row * DD;
  int i = threadIdx.x * 4;
  float4 v = *(const float4*)&xr[i];
  float s = v.x + v.y + v.z + v.w;
  float sq = v.x * v.x + v.y * v.y + v.z * v.z + v.w * v.w;
#pragma unroll
  for (int m = 1; m <= 32; m <<= 1) { s += __shfl_xor(s, m); sq += __shfl_xor(sq, m); }
  __shared__ float rs[4], rq[4];
  int wid = threadIdx.x >> 6;
  if ((threadIdx.x & 63) == 0) { rs[wid] = s; rq[wid] = sq; }
  __syncthreads();
  s = rs[0] + rs[1] + rs[2] + rs[3];
  sq = rq[0] + rq[1] + rq[2] + rq[3];
  float mean = s * (1.f / DD);
  float var = sq * (1.f / DD) - mean * mean;
  float rstd = rsqrtf(var + 1e-5f);
  float4 gv = *(const float4*)&g[i];
  float4 bv = *(const float4*)&bt[i];
  __bf16* yr = y + (size_t)row * DD + i;
  yr[0] = (__bf16)((v.x - mean) * rstd * gv.x + bv.x);
  yr[1] = (__bf16)((v.y - mean) * rstd * gv.y + bv.y);
  yr[2] = (__bf16)((v.z - mean) * rstd * gv.z + bv.z);
  yr[3] = (__bf16)((v.w - mean) * rstd * gv.w + bv.w);
}

// ---------- GEMM: C[M,N] = A[M,K] * Bw[N,K]^T, templated epilogue ----------
template <int EPI>
__global__ __launch_bounds__(256) void k_gemm(const __bf16* __restrict__ A,
                                              const __bf16* __restrict__ Bw, int K,
                                              const float* __restrict__ bias,
                                              const float* __restrict__ aux1,
                                              const float* __restrict__ aux2,
                                              float* __restrict__ outf,
                                              __bf16* __restrict__ outb) {
  __shared__ __bf16 aS[2][128 * 32];
  __shared__ __bf16 bS[2][128 * 32];
  const int tid = threadIdx.x;
  const int lane = tid & 63;
  const int wid = tid >> 6;
  const int wm = wid >> 1, wn = wid & 1;
  const int r = lane & 15, gq = lane >> 4;
  const int m0 = blockIdx.y * 128;
  const int n0 = blockIdx.x * 128;

  f32x4 acc[4][4];
#pragma unroll
  for (int mi = 0; mi < 4; ++mi)
#pragma unroll
    for (int ni = 0; ni < 4; ++ni) acc[mi][ni] = (f32x4){0.f, 0.f, 0.f, 0.f};

  auto stage = [&](int bufi, int k0) {
#pragma unroll
    for (int i = 0; i < 2; ++i) {
      int e = i * 2048 + tid * 8;
      int row = e >> 5, col = e & 31;
      gload_lds16(A + (size_t)(m0 + row) * K + k0 + col, &aS[bufi][e]);
      gload_lds16(Bw + (size_t)(n0 + row) * K + k0 + col, &bS[bufi][e]);
    }
  };

  stage(0, 0);
  const int nk = K >> 5;
  int buf = 0;
  for (int kt = 0; kt < nk; ++kt) {
    __syncthreads();
    if (kt + 1 < nk) stage(buf ^ 1, (kt + 1) << 5);
    bf16x8 af[4], bfr[4];
#pragma unroll
    for (int mi = 0; mi < 4; ++mi)
      af[mi] = *reinterpret_cast<const bf16x8*>(&aS[buf][(wm * 64 + mi * 16 + r) * 32 + gq * 8]);
#pragma unroll
    for (int ni = 0; ni < 4; ++ni)
      bfr[ni] = *reinterpret_cast<const bf16x8*>(&bS[buf][(wn * 64 + ni * 16 + r) * 32 + gq * 8]);
#pragma unroll
    for (int mi = 0; mi < 4; ++mi)
#pragma unroll
      for (int ni = 0; ni < 4; ++ni)
        acc[mi][ni] = __builtin_amdgcn_mfma_f32_16x16x32_bf16(af[mi], bfr[ni], acc[mi][ni], 0, 0, 0);
    buf ^= 1;
  }

#pragma unroll
  for (int mi = 0; mi < 4; ++mi) {
#pragma unroll
    for (int ni = 0; ni < 4; ++ni) {
      int colg = n0 + wn * 64 + ni * 16 + r;
      float bcol = bias[colg];
#pragma unroll
      for (int rr = 0; rr < 4; ++rr) {
        int mg = m0 + wm * 64 + mi * 16 + gq * 4 + rr;
        float val = acc[mi][ni][rr] + bcol;
        if constexpr (EPI == 0) {
          int which = colg >> 10, e = colg & 1023;
          int hh = e >> 6, d = e & 63;
          int b = mg >> 11, nq = mg & (NN - 1);
          if (which == 2) {
            // V^T (b,h,d,n) with within-64 k-permutation sigma baked in
            int nl = nq & 63, kk = nl & 31;
            int slot = ((kk >> 4) << 2) | (((kk >> 2) & 3) << 3) | (kk & 3) | (nl & 32);
            int nqp = (nq & ~63) | slot;
            outb[(size_t)2 * (BB * HH * NN * HD) +
                 ((size_t)((b * HH + hh) * HD + d)) * NN + nqp] = (__bf16)val;
          } else {
            outb[(size_t)which * (BB * HH * NN * HD) +
                 ((size_t)(b * HH + hh) * NN + nq) * HD + d] = (__bf16)val;
          }
        } else if constexpr (EPI == 1) {
          size_t idx = (size_t)mg * DD + colg;
          outf[idx] = aux1[idx] + val;
        } else if constexpr (EPI == 2) {
          float gl = val * 0.5f * (1.f + erff(val * 0.70710678118f));
          outb[(size_t)mg * HID_ + colg] = (__bf16)gl;
        } else {
          size_t idx = (size_t)mg * DD + colg;
          outf[idx] = val + aux1[idx] + aux2[idx];
        }
      }
    }
  }
}

// ---------- flash attention v3: swapped QK^T, lane-local softmax, no P bounce ----------
__global__ __launch_bounds__(256) void k_attn(const __bf16* __restrict__ qb,
                                              const __bf16* __restrict__ kb,
                                              const __bf16* __restrict__ vtb,
                                              const __bf16* __restrict__ pbt,
                                              __bf16* __restrict__ ob) {
  __shared__ __bf16 kS[2][64 * 64];
  __shared__ __bf16 vS[2][64 * 64];
  int blk = blockIdx.x;
  int qt = blk & 31, bh = blk >> 5;
  int h = bh & (HH - 1), b = bh >> 4;
  int tid = threadIdx.x;
  int lane = tid & 63, w = tid >> 6;
  int r = lane & 15, g = lane >> 4;
  const __bf16* Kp = kb + (size_t)bh * NN * HD;
  const __bf16* Vt = vtb + (size_t)bh * HD * NN;
  int qbase = qt * 64 + w * 16;
  const __bf16* Q = qb + ((size_t)bh * NN + qbase) * HD;

  bf16x8 qf0 = *(const bf16x8*)&Q[(size_t)r * HD + g * 8];
  bf16x8 qf1 = *(const bf16x8*)&Q[(size_t)r * HD + 32 + g * 8];
  bf16x8 onesf;
#pragma unroll
  for (int j = 0; j < 8; ++j) onesf[j] = (__bf16)1.0f;

  const float C = 0.18033688011112042f;          // 0.125 * log2(e)
  const float THRL2 = 11.541560327111707f;       // 8 * log2(e)
  float slope = exp2f(-0.5f * (float)(h + 1)) * 1.4426950408889634f;  // log2-domain
  float sconst[16];
#pragma unroll
  for (int st = 0; st < 4; ++st)
#pragma unroll
    for (int rr = 0; rr < 4; ++rr) sconst[st * 4 + rr] = slope * (float)(st * 16 + rr);
  float aL = slope * (float)(g * 4 - r);

  // m starts at 0 (NOT -inf): first chunk's zm are then raw log2-logits and the
  // rescale (if triggered) computes delta exactly; P <= 2^THRL2 otherwise (T13).
  // m = -1e30 caused catastrophic cancellation (zm+1e30 rounds to 1e30 -> P==1).
  float m = 0.f;
  f32x4 oacc[4], lacc;
#pragma unroll
  for (int t = 0; t < 4; ++t) oacc[t] = (f32x4){0.f, 0.f, 0.f, 0.f};
  lacc = (f32x4){0.f, 0.f, 0.f, 0.f};

  auto stage = [&](int bufi, int kc0) {
#pragma unroll
    for (int i = 0; i < 2; ++i) {
      int idx = i * 256 + tid;
      int row = idx >> 3;
      int c = (idx & 7) * 8;
      int src = c ^ ((row & 7) * 8);
      gload_lds16(Kp + (size_t)(kc0 + row) * HD + src, &kS[bufi][idx * 8]);
    }
#pragma unroll
    for (int i = 0; i < 2; ++i) {
      int idx = i * 256 + tid;
      int row = idx >> 3;
      int c = (idx & 7) * 8;
      int src = c ^ ((row & 7) * 8);
      gload_lds16(Vt + (size_t)row * NN + kc0 + src, &vS[bufi][idx * 8]);
    }
  };

  stage(0, 0);
  int buf = 0;
  size_t tilebase = (size_t)(qt * 4 + w) * 128;
  int sw = (r & 7) * 8;

  for (int ch = 0; ch < NN / 64; ++ch) {
    int kc0 = ch * 64;
    __syncthreads();
    if (ch + 1 < NN / 64) stage(buf ^ 1, kc0 + 64);

    // periodic bias (pre-scaled by log2e), one 8B load per 16-k subtile
    uint2 ub[4];
#pragma unroll
    for (int st = 0; st < 4; ++st)
      ub[st] = *(const uint2*)&pbt[(tilebase + (kc0 >> 4) + st) * 256 + lane * 4];

    // swapped QK^T: D[k][q]; lane (r,g) holds q=r, k = st*16 + g*4 + rr
    f32x4 sacc[4];
#pragma unroll
    for (int st = 0; st < 4; ++st) {
      sacc[st] = (f32x4){0.f, 0.f, 0.f, 0.f};
      int rowb = (st * 16 + r) * 64;
      bf16x8 kf0 = *(const bf16x8*)&kS[buf][rowb + ((g * 8) ^ sw)];
      bf16x8 kf1 = *(const bf16x8*)&kS[buf][rowb + ((32 + g * 8) ^ sw)];
      sacc[st] = __builtin_amdgcn_mfma_f32_16x16x32_bf16(kf0, qf0, sacc[st], 0, 0, 0);
      sacc[st] = __builtin_amdgcn_mfma_f32_16x16x32_bf16(kf1, qf1, sacc[st], 0, 0, 0);
    }

    // zm = logit(log2 domain) - m
    float zm[16];
    if (ch > qt) {
      float uu = fmaf(slope, (float)(kc0 - qbase), aL) + m;
#pragma unroll
      for (int st = 0; st < 4; ++st) {
        float p0 = __uint_as_float(ub[st].x << 16);
        float p1 = __uint_as_float(ub[st].x & 0xffff0000u);
        float p2 = __uint_as_float(ub[st].y << 16);
        float p3 = __uint_as_float(ub[st].y & 0xffff0000u);
        zm[st*4+0] = fmaf(sacc[st][0], C, p0) - uu - sconst[st*4+0];
        zm[st*4+1] = fmaf(sacc[st][1], C, p1) - uu - sconst[st*4+1];
        zm[st*4+2] = fmaf(sacc[st][2], C, p2) - uu - sconst[st*4+2];
        zm[st*4+3] = fmaf(sacc[st][3], C, p3) - uu - sconst[st*4+3];
      }
    } else if (ch < qt) {
#pragma unroll
      for (int st = 0; st < 4; ++st) {
        float p0 = __uint_as_float(ub[st].x << 16);
        float p1 = __uint_as_float(ub[st].x & 0xffff0000u);
        float p2 = __uint_as_float(ub[st].y << 16);
        float p3 = __uint_as_float(ub[st].y & 0xffff0000u);
        zm[st*4+0] = fmaf(sacc[st][0], C, p0) - m;
        zm[st*4+1] = fmaf(sacc[st][1], C, p1) - m;
        zm[st*4+2] = fmaf(sacc[st][2], C, p2) - m;
        zm[st*4+3] = fmaf(sacc[st][3], C, p3) - m;
      }
    } else {
      int kqb = kc0 + g * 4 - qbase - r;
#pragma unroll
      for (int st = 0; st < 4; ++st) {
        float p0 = __uint_as_float(ub[st].x << 16);
        float p1 = __uint_as_float(ub[st].x & 0xffff0000u);
        float p2 = __uint_as_float(ub[st].y << 16);
        float p3 = __uint_as_float(ub[st].y & 0xffff0000u);
        float pb4[4] = {p0, p1, p2, p3};
#pragma unroll
        for (int rr = 0; rr < 4; ++rr) {
          int dk = kqb + st * 16 + rr;
          float dist = (dk > 0) ? (float)dk : 0.f;
          zm[st*4+rr] = fmaf(sacc[st][rr], C, pb4[rr]) - fmaf(slope, dist, m);
        }
      }
    }

    // deferred max
    float zmax = zm[0];
#pragma unroll
    for (int j = 1; j < 16; ++j) zmax = fmaxf(zmax, zm[j]);
    if (__any(zmax > THRL2)) {
      float rowmax = fmaxf(zmax, __shfl_xor(zmax, 16));
      rowmax = fmaxf(rowmax, __shfl_xor(rowmax, 32));
      float delta = fmaxf(rowmax, 0.f);
      m += delta;
      float sc = exp2f(-delta);
      float sco[4];
#pragma unroll
      for (int rr = 0; rr < 4; ++rr) sco[rr] = __shfl(sc, g * 4 + rr);
#pragma unroll
      for (int rr = 0; rr < 4; ++rr) {
        lacc[rr] *= sco[rr];
#pragma unroll
        for (int t = 0; t < 4; ++t) oacc[t][rr] *= sco[rr];
      }
#pragma unroll
      for (int j = 0; j < 16; ++j) zm[j] -= delta;
    }

    // exp2 + pack straight into PV A-fragments (k-perm matches V's sigma layout)
    bf16x8 pa0, pa1;
#pragma unroll
    for (int j = 0; j < 8; ++j) {
      pa0[j] = (__bf16)exp2f(zm[(j >> 2) * 4 + (j & 3)]);
      pa1[j] = (__bf16)exp2f(zm[(2 + (j >> 2)) * 4 + (j & 3)]);
    }

    // PV + row-sum
#pragma unroll
    for (int t = 0; t < 4; ++t) {
      int rowb = (t * 16 + r) * 64;
      bf16x8 vf0 = *(const bf16x8*)&vS[buf][rowb + ((g * 8) ^ sw)];
      bf16x8 vf1 = *(const bf16x8*)&vS[buf][rowb + ((32 + g * 8) ^ sw)];
      oacc[t] = __builtin_amdgcn_mfma_f32_16x16x32_bf16(pa0, vf0, oacc[t], 0, 0, 0);
      oacc[t] = __builtin_amdgcn_mfma_f32_16x16x32_bf16(pa1, vf1, oacc[t], 0, 0, 0);
    }
    lacc = __builtin_amdgcn_mfma_f32_16x16x32_bf16(pa0, onesf, lacc, 0, 0, 0);
    lacc = __builtin_amdgcn_mfma_f32_16x16x32_bf16(pa1, onesf, lacc, 0, 0, 0);
    buf ^= 1;
  }

  // normalize + write o (B,N,H*64)
#pragma unroll
  for (int rr = 0; rr < 4; ++rr) {
    int qg = qbase + g * 4 + rr;
    float inv = 1.f / lacc[rr];
#pragma unroll
    for (int t = 0; t < 4; ++t) {
      float v = oacc[t][rr] * inv;
      ob[((size_t)(b * NN) + qg) * DD + h * HD + t * 16 + r] = (__bf16)v;
    }
  }
}

__global__ void k_tail(float* __restrict__ out) { out[(size_t)BB * NN * DD] = 0.f; }

extern "C" void kernel_launch(void* const* d_in, const int* in_sizes, int n_in,
                              void* d_out, int out_size, void* d_ws, size_t ws_size,
                              hipStream_t stream) {
  const float* x    = (const float*)d_in[0];
  const float* pb   = (const float*)d_in[1];
  const float* alpha= (const float*)d_in[2];
  const float* dw7  = (const float*)d_in[3];
  const float* dw25 = (const float*)d_in[4];
  const float* dw49 = (const float*)d_in[5];
  const float* ln1g = (const float*)d_in[6];
  const float* ln1b = (const float*)d_in[7];
  const float* ln2g = (const float*)d_in[8];
  const float* ln2b = (const float*)d_in[9];
  const float* Wq   = (const float*)d_in[10];
  const float* bq   = (const float*)d_in[11];
  const float* Wk   = (const float*)d_in[12];
  const float* bk   = (const float*)d_in[13];
  const float* Wv   = (const float*)d_in[14];
  const float* bv   = (const float*)d_in[15];
  const float* Wo   = (const float*)d_in[16];
  const float* bo   = (const float*)d_in[17];
  const float* W1   = (const float*)d_in[18];
  const float* b1   = (const float*)d_in[19];
  const float* W2   = (const float*)d_in[20];
  const float* b2   = (const float*)d_in[21];
  const float* tw   = (const float*)d_in[22];
  const float* tb   = (const float*)d_in[23];
  float* out = (float*)d_out;

  char* w = (char*)d_ws;
  size_t off = 0;
  auto alloc = [&](size_t bytes) -> char* {
    char* p = w + off;
    off = (off + bytes + 255) & ~(size_t)255;
    return p;
  };
  float*  wc    = (float*)alloc(49 * 1024 * 4);
  float*  b3    = (float*)alloc(3072 * 4);
  float*  Tbuf  = (float*)alloc((size_t)MM * DD * 4);
  float*  Sbuf  = (float*)alloc((size_t)MM * DD * 4);
  float*  toutb = (float*)alloc((size_t)MM * DD * 4);
  __bf16* sn    = (__bf16*)alloc((size_t)MM * DD * 2);
  __bf16* qkv   = (__bf16*)alloc((size_t)3 * MM * DD * 2);
  __bf16* gb    = (__bf16*)alloc((size_t)MM * HID_ * 2);
  __bf16* wall  = (__bf16*)alloc((size_t)12582912 * 2);
  __bf16* pbt   = (__bf16*)alloc((size_t)NN * NN * 2);
  __bf16* wqkvb = wall;
  __bf16* wob   = wall + (size_t)3 * DD * DD;
  __bf16* w1b   = wall + (size_t)4 * DD * DD;
  __bf16* w2b   = wall + (size_t)4 * DD * DD + (size_t)HID_ * DD;
  float*  xs    = Tbuf;   // alias: T dead after k_tout
  __bf16* obuf  = sn;     // alias: sn dead after QKV gemm
  __bf16* hb    = qkv;    // alias: q dead after attention

  const size_t BHND = (size_t)BB * HH * NN * HD;

  k_wcomb<<<49, 256, 0, stream>>>(alpha, dw7, dw25, dw49, wc);
  k_bias3<<<1, 256, 0, stream>>>(bq, bk, bv, b3);
  k_pbt<<<NN, 256, 0, stream>>>(pb, pbt);
  k_cvtall<<<12288, 256, 0, stream>>>(Wq, Wk, Wv, Wo, W1, W2, wall);
  k_decomp<<<1024, 256, 0, stream>>>(x, wc, Tbuf, Sbuf);
  k_tout<<<1024, 256, 0, stream>>>(Tbuf, tw, tb, toutb);
  k_ln<<<MM, 256, 0, stream>>>(Sbuf, ln1g, ln1b, sn);
  k_gemm<0><<<dim3(24, 32), 256, 0, stream>>>(sn, wqkvb, DD, b3, nullptr, nullptr, nullptr, qkv);
  k_attn<<<BB * HH * (NN / 64), 256, 0, stream>>>(qkv, qkv + BHND, qkv + 2 * BHND, pbt, obuf);
  k_gemm<1><<<dim3(8, 32), 256, 0, stream>>>(obuf, wob, DD, bo, Sbuf, nullptr, xs, nullptr);
  k_ln<<<MM, 256, 0, stream>>>(xs, ln2g, ln2b, hb);
  k_gemm<2><<<dim3(32, 32), 256, 0, stream>>>(hb, w1b, DD, b1, nullptr, nullptr, nullptr, gb);
  k_gemm<3><<<dim3(8, 32), 256, 0, stream>>>(gb, w2b, HID_, b2, xs, toutb, out, nullptr);
  k_tail<<<1, 1, 0, stream>>>(out);
}

// Round 5
// 353.606 us; speedup vs baseline: 1.6960x; 1.0924x over previous
//
#include <hip/hip_runtime.h>
#include <cstdint>

#define BB 2
#define NN 2048
#define DD 1024
#define HH 16
#define HD 64
#define HID_ 4096
#define MM (BB*NN)

typedef __bf16 bf16x8 __attribute__((ext_vector_type(8)));
typedef float  f32x4  __attribute__((ext_vector_type(4)));

__device__ inline void gload_lds16(const void* g, void* l) {
  __builtin_amdgcn_global_load_lds((const __attribute__((address_space(1))) char*)g,
                                   (__attribute__((address_space(3))) char*)l, 16, 0, 0);
}

// ---------- prep: combined decomposition weights ----------
__global__ void k_wcomb(const float* __restrict__ alpha, const float* __restrict__ dw7,
                        const float* __restrict__ dw25, const float* __restrict__ dw49,
                        float* __restrict__ wc) {
  int t = blockIdx.x;  // 0..48
  float a0 = alpha[0], a1 = alpha[1], a2 = alpha[2];
  float mx = fmaxf(a0, fmaxf(a1, a2));
  float e0 = __expf(a0 - mx), e1 = __expf(a1 - mx), e2 = __expf(a2 - mx);
  float inv = 1.f / (e0 + e1 + e2);
  float w0 = e0 * inv, w1 = e1 * inv, w2 = e2 * inv;
  for (int d = threadIdx.x; d < DD; d += blockDim.x) {
    float v = w2 * dw49[d * 49 + t];
    if (t >= 12 && t <= 36) v += w1 * dw25[d * 25 + (t - 12)];
    if (t >= 21 && t <= 27) v += w0 * dw7[d * 7 + (t - 21)];
    wc[t * DD + d] = v;
  }
}

__global__ void k_bias3(const float* __restrict__ bq, const float* __restrict__ bk,
                        const float* __restrict__ bv, float* __restrict__ b3) {
  for (int i = threadIdx.x; i < 3 * DD; i += blockDim.x) {
    const float* s = (i < DD) ? bq : (i < 2 * DD ? bk : bv);
    b3[i] = s[i & (DD - 1)];
  }
}

// all weight converts in one launch; dst = [qkv 3M][wo 1M][w1 4M][w2 4M]
__global__ __launch_bounds__(256) void k_cvtall(const float* __restrict__ Wq, const float* __restrict__ Wk,
                         const float* __restrict__ Wv, const float* __restrict__ Wo,
                         const float* __restrict__ W1, const float* __restrict__ W2,
                         __bf16* __restrict__ dst) {
  size_t i = ((size_t)blockIdx.x * 256 + threadIdx.x) * 4;
  const float* s;
  if (i < 1048576u) s = Wq + i;
  else if (i < 2097152u) s = Wk + (i - 1048576u);
  else if (i < 3145728u) s = Wv + (i - 2097152u);
  else if (i < 4194304u) s = Wo + (i - 3145728u);
  else if (i < 8388608u) s = W1 + (i - 4194304u);
  else s = W2 + (i - 8388608u);
  float4 v = *(const float4*)s;
  dst[i] = (__bf16)v.x; dst[i+1] = (__bf16)v.y; dst[i+2] = (__bf16)v.z; dst[i+3] = (__bf16)v.w;
}

// pb -> bf16*log2e, fragment-tiled for swapped-QK^T lane layout:
// element (q,k): tile (q>>4, k>>4), offset ((q&15) + 16*((k>>2)&3))*4 + (k&3)
__global__ __launch_bounds__(256) void k_pbt(const float* __restrict__ pb,
                                             __bf16* __restrict__ pbt) {
  int q = blockIdx.x;
  int qt16 = q >> 4, qm = q & 15;
  for (int k = threadIdx.x; k < NN; k += 256) {
    float v = pb[(size_t)q * NN + k] * 1.4426950408889634f;
    int kt = k >> 4, g = (k >> 2) & 3, rr = k & 3;
    pbt[((size_t)qt16 * 128 + kt) * 256 + (qm + 16 * g) * 4 + rr] = (__bf16)v;
  }
}

// ---------- series decomposition: register sliding window, 16-row strips ----------
__global__ __launch_bounds__(256) void k_decomp(const float* __restrict__ x,
                                                const float* __restrict__ wc,
                                                float* __restrict__ T, float* __restrict__ S) {
  int bid = blockIdx.x;
  int db = bid & 3, ns = (bid >> 2) & 127, b = bid >> 9;
  int d = db * 256 + threadIdx.x;
  const float* xb = x + (size_t)b * NN * DD + d;
  float xw[64];
#pragma unroll
  for (int i = 0; i < 64; ++i) {
    int n = ns * 16 - 24 + i;
    n = (n < 0) ? -n : n;
    n = (n > NN - 1) ? 2 * (NN - 1) - n : n;
    xw[i] = xb[(size_t)n * DD];
  }
  float acc[16];
#pragma unroll
  for (int i = 0; i < 16; ++i) acc[i] = 0.f;
#pragma unroll
  for (int t = 0; t < 49; ++t) {
    float wv = wc[t * DD + d];
#pragma unroll
    for (int i = 0; i < 16; ++i) acc[i] = fmaf(wv, xw[i + t], acc[i]);
  }
  size_t base = ((size_t)b * NN + ns * 16) * DD + d;
#pragma unroll
  for (int i = 0; i < 16; ++i) {
    T[base + (size_t)i * DD] = acc[i];
    S[base + (size_t)i * DD] = xw[i + 24] - acc[i];
  }
}

// ---------- trend conv k=5, zero pad: sliding window ----------
__global__ __launch_bounds__(256) void k_tout(const float* __restrict__ T,
                                              const float* __restrict__ tw,
                                              const float* __restrict__ tb,
                                              float* __restrict__ tout) {
  int bid = blockIdx.x;
  int db = bid & 3, ns = (bid >> 2) & 127, b = bid >> 9;
  int d = db * 256 + threadIdx.x;
  const float* Tb = T + (size_t)b * NN * DD + d;
  float xw[20];
#pragma unroll
  for (int i = 0; i < 20; ++i) {
    int n = ns * 16 - 2 + i;
    xw[i] = (n < 0 || n >= NN) ? 0.f : Tb[(size_t)n * DD];
  }
  float bv = tb[d];
  float acc[16];
#pragma unroll
  for (int i = 0; i < 16; ++i) acc[i] = bv;
#pragma unroll
  for (int t = 0; t < 5; ++t) {
    float wv = tw[d * 5 + t];
#pragma unroll
    for (int i = 0; i < 16; ++i) acc[i] = fmaf(wv, xw[i + t], acc[i]);
  }
  size_t base = ((size_t)b * NN + ns * 16) * DD + d;
#pragma unroll
  for (int i = 0; i < 16; ++i) tout[base + (size_t)i * DD] = acc[i];
}

// ---------- LayerNorm (fp32 in -> bf16 out) ----------
__global__ __launch_bounds__(256) void k_ln(const float* __restrict__ x,
                                            const float* __restrict__ g,
                                            const float* __restrict__ bt,
                                            __bf16* __restrict__ y) {
  int row = blockIdx.x;
  const float* xr = x + (size_t)row * DD;
  int i = threadIdx.x * 4;
  float4 v = *(const float4*)&xr[i];
  float s = v.x + v.y + v.z + v.w;
  float sq = v.x * v.x + v.y * v.y + v.z * v.z + v.w * v.w;
#pragma unroll
  for (int m = 1; m <= 32; m <<= 1) { s += __shfl_xor(s, m); sq += __shfl_xor(sq, m); }
  __shared__ float rs[4], rq[4];
  int wid = threadIdx.x >> 6;
  if ((threadIdx.x & 63) == 0) { rs[wid] = s; rq[wid] = sq; }
  __syncthreads();
  s = rs[0] + rs[1] + rs[2] + rs[3];
  sq = rq[0] + rq[1] + rq[2] + rq[3];
  float mean = s * (1.f / DD);
  float var = sq * (1.f / DD) - mean * mean;
  float rstd = rsqrtf(var + 1e-5f);
  float4 gv = *(const float4*)&g[i];
  float4 bv = *(const float4*)&bt[i];
  __bf16* yr = y + (size_t)row * DD + i;
  yr[0] = (__bf16)((v.x - mean) * rstd * gv.x + bv.x);
  yr[1] = (__bf16)((v.y - mean) * rstd * gv.y + bv.y);
  yr[2] = (__bf16)((v.z - mean) * rstd * gv.z + bv.z);
  yr[3] = (__bf16)((v.w - mean) * rstd * gv.w + bv.w);
}

// ---------- GEMM: C[M,N] = A[M,K] * Bw[N,K]^T, tile 128 x BNT ----------
// EPI 0: QKV permute+bias (V^T with sigma perm); 1: O-proj + residual;
// EPI 2: FFN1 gelu->bf16; 3: FFN2 + x_s + t_out -> out
template <int EPI, int BNT>
__global__ __launch_bounds__(256) void k_gemm(const __bf16* __restrict__ A,
                                              const __bf16* __restrict__ Bw, int K,
                                              const float* __restrict__ bias,
                                              const float* __restrict__ aux1,
                                              const float* __restrict__ aux2,
                                              float* __restrict__ outf,
                                              __bf16* __restrict__ outb) {
  constexpr int NFR = BNT / 32;   // b-frags per wave per K-step
  __shared__ __bf16 aS[2][128 * 32];
  __shared__ __bf16 bS[2][BNT * 32];
  const int tid = threadIdx.x;
  const int lane = tid & 63;
  const int wid = tid >> 6;
  const int wm = wid >> 1, wn = wid & 1;
  const int r = lane & 15, gq = lane >> 4;
  const int m0 = blockIdx.y * 128;
  const int n0 = blockIdx.x * BNT;

  f32x4 acc[4][NFR];
#pragma unroll
  for (int mi = 0; mi < 4; ++mi)
#pragma unroll
    for (int ni = 0; ni < NFR; ++ni) acc[mi][ni] = (f32x4){0.f, 0.f, 0.f, 0.f};

  auto stage = [&](int bufi, int k0) {
#pragma unroll
    for (int i = 0; i < 2; ++i) {
      int e = i * 2048 + tid * 8;
      int row = e >> 5, col = e & 31;
      gload_lds16(A + (size_t)(m0 + row) * K + k0 + col, &aS[bufi][e]);
    }
#pragma unroll
    for (int i = 0; i < BNT / 64; ++i) {
      int e = i * 2048 + tid * 8;
      int row = e >> 5, col = e & 31;
      gload_lds16(Bw + (size_t)(n0 + row) * K + k0 + col, &bS[bufi][e]);
    }
  };

  stage(0, 0);
  const int nk = K >> 5;
  int buf = 0;
  for (int kt = 0; kt < nk; ++kt) {
    __syncthreads();
    if (kt + 1 < nk) stage(buf ^ 1, (kt + 1) << 5);
    bf16x8 af[4], bfr[NFR];
#pragma unroll
    for (int mi = 0; mi < 4; ++mi)
      af[mi] = *reinterpret_cast<const bf16x8*>(&aS[buf][(wm * 64 + mi * 16 + r) * 32 + gq * 8]);
#pragma unroll
    for (int ni = 0; ni < NFR; ++ni)
      bfr[ni] = *reinterpret_cast<const bf16x8*>(&bS[buf][(wn * (BNT / 2) + ni * 16 + r) * 32 + gq * 8]);
#pragma unroll
    for (int mi = 0; mi < 4; ++mi)
#pragma unroll
      for (int ni = 0; ni < NFR; ++ni)
        acc[mi][ni] = __builtin_amdgcn_mfma_f32_16x16x32_bf16(af[mi], bfr[ni], acc[mi][ni], 0, 0, 0);
    buf ^= 1;
  }

#pragma unroll
  for (int mi = 0; mi < 4; ++mi) {
#pragma unroll
    for (int ni = 0; ni < NFR; ++ni) {
      int colg = n0 + wn * (BNT / 2) + ni * 16 + r;
      float bcol = bias[colg];
#pragma unroll
      for (int rr = 0; rr < 4; ++rr) {
        int mg = m0 + wm * 64 + mi * 16 + gq * 4 + rr;
        float val = acc[mi][ni][rr] + bcol;
        if constexpr (EPI == 0) {
          int which = colg >> 10, e = colg & 1023;
          int hh = e >> 6, d = e & 63;
          int b = mg >> 11, nq = mg & (NN - 1);
          if (which == 2) {
            // V^T (b,h,d,n) with within-64 k-permutation sigma baked in
            int nl = nq & 63, kk = nl & 31;
            int slot = ((kk >> 4) << 2) | (((kk >> 2) & 3) << 3) | (kk & 3) | (nl & 32);
            int nqp = (nq & ~63) | slot;
            outb[(size_t)2 * (BB * HH * NN * HD) +
                 ((size_t)((b * HH + hh) * HD + d)) * NN + nqp] = (__bf16)val;
          } else {
            outb[(size_t)which * (BB * HH * NN * HD) +
                 ((size_t)(b * HH + hh) * NN + nq) * HD + d] = (__bf16)val;
          }
        } else if constexpr (EPI == 1) {
          size_t idx = (size_t)mg * DD + colg;
          outf[idx] = aux1[idx] + val;
        } else if constexpr (EPI == 2) {
          float gl = val * 0.5f * (1.f + erff(val * 0.70710678118f));
          outb[(size_t)mg * HID_ + colg] = (__bf16)gl;
        } else {
          size_t idx = (size_t)mg * DD + colg;
          outf[idx] = val + aux1[idx] + aux2[idx];
        }
      }
    }
  }
}

// ---------- flash attention v4: 8 waves/block (QBLK=128), shared K/V staging ----------
__global__ __launch_bounds__(512) void k_attn(const __bf16* __restrict__ qb,
                                              const __bf16* __restrict__ kb,
                                              const __bf16* __restrict__ vtb,
                                              const __bf16* __restrict__ pbt,
                                              __bf16* __restrict__ ob) {
  __shared__ __bf16 kS[2][64 * 64];
  __shared__ __bf16 vS[2][64 * 64];
  int blk = blockIdx.x;
  int qt = blk & 15, bh = blk >> 4;      // NN/128 = 16 q-tiles per bh
  int h = bh & (HH - 1), b = bh >> 4;
  int tid = threadIdx.x;
  int lane = tid & 63, w = tid >> 6;     // 8 waves
  int r = lane & 15, g = lane >> 4;
  const __bf16* Kp = kb + (size_t)bh * NN * HD;
  const __bf16* Vt = vtb + (size_t)bh * HD * NN;
  int qbase = qt * 128 + w * 16;
  int cq = qt * 2 + (w >> 2);            // 64-chunk containing this wave's q rows
  const __bf16* Q = qb + ((size_t)bh * NN + qbase) * HD;

  bf16x8 qf0 = *(const bf16x8*)&Q[(size_t)r * HD + g * 8];
  bf16x8 qf1 = *(const bf16x8*)&Q[(size_t)r * HD + 32 + g * 8];
  bf16x8 onesf;
#pragma unroll
  for (int j = 0; j < 8; ++j) onesf[j] = (__bf16)1.0f;

  const float C = 0.18033688011112042f;          // 0.125 * log2(e)
  const float THRL2 = 11.541560327111707f;       // 8 * log2(e)
  float slope = exp2f(-0.5f * (float)(h + 1)) * 1.4426950408889634f;  // log2-domain
  float sconst[16];
#pragma unroll
  for (int st = 0; st < 4; ++st)
#pragma unroll
    for (int rr = 0; rr < 4; ++rr) sconst[st * 4 + rr] = slope * (float)(st * 16 + rr);
  float aL = slope * (float)(g * 4 - r);

  // m starts at 0 (NOT -inf): avoids first-chunk catastrophic cancellation (T13).
  float m = 0.f;
  f32x4 oacc[4], lacc;
#pragma unroll
  for (int t = 0; t < 4; ++t) oacc[t] = (f32x4){0.f, 0.f, 0.f, 0.f};
  lacc = (f32x4){0.f, 0.f, 0.f, 0.f};

  // 512 threads: one 16B gload each for K tile, one for V^T tile (pre-swizzled src)
  auto stage = [&](int bufi, int kc0) {
    int row = tid >> 3;
    int c = (tid & 7) * 8;
    int src = c ^ ((row & 7) * 8);
    gload_lds16(Kp + (size_t)(kc0 + row) * HD + src, &kS[bufi][tid * 8]);
    gload_lds16(Vt + (size_t)row * NN + kc0 + src, &vS[bufi][tid * 8]);
  };

  stage(0, 0);
  int buf = 0;
  size_t tilebase = (size_t)(qt * 8 + w) * 128;
  int sw = (r & 7) * 8;

  for (int ch = 0; ch < NN / 64; ++ch) {
    int kc0 = ch * 64;
    __syncthreads();
    if (ch + 1 < NN / 64) stage(buf ^ 1, kc0 + 64);

    // periodic bias (pre-scaled by log2e), one 8B load per 16-k subtile
    uint2 ub[4];
#pragma unroll
    for (int st = 0; st < 4; ++st)
      ub[st] = *(const uint2*)&pbt[(tilebase + (kc0 >> 4) + st) * 256 + lane * 4];

    // swapped QK^T: D[k][q]; lane (r,g) holds q=r, k = st*16 + g*4 + rr
    f32x4 sacc[4];
#pragma unroll
    for (int st = 0; st < 4; ++st) {
      sacc[st] = (f32x4){0.f, 0.f, 0.f, 0.f};
      int rowb = (st * 16 + r) * 64;
      bf16x8 kf0 = *(const bf16x8*)&kS[buf][rowb + ((g * 8) ^ sw)];
      bf16x8 kf1 = *(const bf16x8*)&kS[buf][rowb + ((32 + g * 8) ^ sw)];
      sacc[st] = __builtin_amdgcn_mfma_f32_16x16x32_bf16(kf0, qf0, sacc[st], 0, 0, 0);
      sacc[st] = __builtin_amdgcn_mfma_f32_16x16x32_bf16(kf1, qf1, sacc[st], 0, 0, 0);
    }

    // zm = logit(log2 domain) - m
    float zm[16];
    if (ch > cq) {
      float uu = fmaf(slope, (float)(kc0 - qbase), aL) + m;
#pragma unroll
      for (int st = 0; st < 4; ++st) {
        float p0 = __uint_as_float(ub[st].x << 16);
        float p1 = __uint_as_float(ub[st].x & 0xffff0000u);
        float p2 = __uint_as_float(ub[st].y << 16);
        float p3 = __uint_as_float(ub[st].y & 0xffff0000u);
        zm[st*4+0] = fmaf(sacc[st][0], C, p0) - uu - sconst[st*4+0];
        zm[st*4+1] = fmaf(sacc[st][1], C, p1) - uu - sconst[st*4+1];
        zm[st*4+2] = fmaf(sacc[st][2], C, p2) - uu - sconst[st*4+2];
        zm[st*4+3] = fmaf(sacc[st][3], C, p3) - uu - sconst[st*4+3];
      }
    } else if (ch < cq) {
#pragma unroll
      for (int st = 0; st < 4; ++st) {
        float p0 = __uint_as_float(ub[st].x << 16);
        float p1 = __uint_as_float(ub[st].x & 0xffff0000u);
        float p2 = __uint_as_float(ub[st].y << 16);
        float p3 = __uint_as_float(ub[st].y & 0xffff0000u);
        zm[st*4+0] = fmaf(sacc[st][0], C, p0) - m;
        zm[st*4+1] = fmaf(sacc[st][1], C, p1) - m;
        zm[st*4+2] = fmaf(sacc[st][2], C, p2) - m;
        zm[st*4+3] = fmaf(sacc[st][3], C, p3) - m;
      }
    } else {
      int kqb = kc0 + g * 4 - qbase - r;
#pragma unroll
      for (int st = 0; st < 4; ++st) {
        float p0 = __uint_as_float(ub[st].x << 16);
        float p1 = __uint_as_float(ub[st].x & 0xffff0000u);
        float p2 = __uint_as_float(ub[st].y << 16);
        float p3 = __uint_as_float(ub[st].y & 0xffff0000u);
        float pb4[4] = {p0, p1, p2, p3};
#pragma unroll
        for (int rr = 0; rr < 4; ++rr) {
          int dk = kqb + st * 16 + rr;
          float dist = (dk > 0) ? (float)dk : 0.f;
          zm[st*4+rr] = fmaf(sacc[st][rr], C, pb4[rr]) - fmaf(slope, dist, m);
        }
      }
    }

    // deferred max (T13)
    float zmax = zm[0];
#pragma unroll
    for (int j = 1; j < 16; ++j) zmax = fmaxf(zmax, zm[j]);
    if (__any(zmax > THRL2)) {
      float rowmax = fmaxf(zmax, __shfl_xor(zmax, 16));
      rowmax = fmaxf(rowmax, __shfl_xor(rowmax, 32));
      float delta = fmaxf(rowmax, 0.f);
      m += delta;
      float sc = exp2f(-delta);
      float sco[4];
#pragma unroll
      for (int rr = 0; rr < 4; ++rr) sco[rr] = __shfl(sc, g * 4 + rr);
#pragma unroll
      for (int rr = 0; rr < 4; ++rr) {
        lacc[rr] *= sco[rr];
#pragma unroll
        for (int t = 0; t < 4; ++t) oacc[t][rr] *= sco[rr];
      }
#pragma unroll
      for (int j = 0; j < 16; ++j) zm[j] -= delta;
    }

    // exp2 + pack straight into PV A-fragments (k-perm matches V's sigma layout)
    bf16x8 pa0, pa1;
#pragma unroll
    for (int j = 0; j < 8; ++j) {
      pa0[j] = (__bf16)exp2f(zm[(j >> 2) * 4 + (j & 3)]);
      pa1[j] = (__bf16)exp2f(zm[(2 + (j >> 2)) * 4 + (j & 3)]);
    }

    // PV + row-sum via ones-column MFMA
#pragma unroll
    for (int t = 0; t < 4; ++t) {
      int rowb = (t * 16 + r) * 64;
      bf16x8 vf0 = *(const bf16x8*)&vS[buf][rowb + ((g * 8) ^ sw)];
      bf16x8 vf1 = *(const bf16x8*)&vS[buf][rowb + ((32 + g * 8) ^ sw)];
      oacc[t] = __builtin_amdgcn_mfma_f32_16x16x32_bf16(pa0, vf0, oacc[t], 0, 0, 0);
      oacc[t] = __builtin_amdgcn_mfma_f32_16x16x32_bf16(pa1, vf1, oacc[t], 0, 0, 0);
    }
    lacc = __builtin_amdgcn_mfma_f32_16x16x32_bf16(pa0, onesf, lacc, 0, 0, 0);
    lacc = __builtin_amdgcn_mfma_f32_16x16x32_bf16(pa1, onesf, lacc, 0, 0, 0);
    buf ^= 1;
  }

  // normalize + write o (B,N,H*64)
#pragma unroll
  for (int rr = 0; rr < 4; ++rr) {
    int qg = qbase + g * 4 + rr;
    float inv = 1.f / lacc[rr];
#pragma unroll
    for (int t = 0; t < 4; ++t) {
      float v = oacc[t][rr] * inv;
      ob[((size_t)(b * NN) + qg) * DD + h * HD + t * 16 + r] = (__bf16)v;
    }
  }
}

__global__ void k_tail(float* __restrict__ out) { out[(size_t)BB * NN * DD] = 0.f; }

extern "C" void kernel_launch(void* const* d_in, const int* in_sizes, int n_in,
                              void* d_out, int out_size, void* d_ws, size_t ws_size,
                              hipStream_t stream) {
  const float* x    = (const float*)d_in[0];
  const float* pb   = (const float*)d_in[1];
  const float* alpha= (const float*)d_in[2];
  const float* dw7  = (const float*)d_in[3];
  const float* dw25 = (const float*)d_in[4];
  const float* dw49 = (const float*)d_in[5];
  const float* ln1g = (const float*)d_in[6];
  const float* ln1b = (const float*)d_in[7];
  const float* ln2g = (const float*)d_in[8];
  const float* ln2b = (const float*)d_in[9];
  const float* Wq   = (const float*)d_in[10];
  const float* bq   = (const float*)d_in[11];
  const float* Wk   = (const float*)d_in[12];
  const float* bk   = (const float*)d_in[13];
  const float* Wv   = (const float*)d_in[14];
  const float* bv   = (const float*)d_in[15];
  const float* Wo   = (const float*)d_in[16];
  const float* bo   = (const float*)d_in[17];
  const float* W1   = (const float*)d_in[18];
  const float* b1   = (const float*)d_in[19];
  const float* W2   = (const float*)d_in[20];
  const float* b2   = (const float*)d_in[21];
  const float* tw   = (const float*)d_in[22];
  const float* tb   = (const float*)d_in[23];
  float* out = (float*)d_out;

  char* w = (char*)d_ws;
  size_t off = 0;
  auto alloc = [&](size_t bytes) -> char* {
    char* p = w + off;
    off = (off + bytes + 255) & ~(size_t)255;
    return p;
  };
  float*  wc    = (float*)alloc(49 * 1024 * 4);
  float*  b3    = (float*)alloc(3072 * 4);
  float*  Tbuf  = (float*)alloc((size_t)MM * DD * 4);
  float*  Sbuf  = (float*)alloc((size_t)MM * DD * 4);
  float*  toutb = (float*)alloc((size_t)MM * DD * 4);
  __bf16* sn    = (__bf16*)alloc((size_t)MM * DD * 2);
  __bf16* qkv   = (__bf16*)alloc((size_t)3 * MM * DD * 2);
  __bf16* gb    = (__bf16*)alloc((size_t)MM * HID_ * 2);
  __bf16* wall  = (__bf16*)alloc((size_t)12582912 * 2);
  __bf16* pbt   = (__bf16*)alloc((size_t)NN * NN * 2);
  __bf16* wqkvb = wall;
  __bf16* wob   = wall + (size_t)3 * DD * DD;
  __bf16* w1b   = wall + (size_t)4 * DD * DD;
  __bf16* w2b   = wall + (size_t)4 * DD * DD + (size_t)HID_ * DD;
  float*  xs    = Tbuf;   // alias: T dead after k_tout
  __bf16* obuf  = sn;     // alias: sn dead after QKV gemm
  __bf16* hb    = qkv;    // alias: q dead after attention

  const size_t BHND = (size_t)BB * HH * NN * HD;

  k_wcomb<<<49, 256, 0, stream>>>(alpha, dw7, dw25, dw49, wc);
  k_bias3<<<1, 256, 0, stream>>>(bq, bk, bv, b3);
  k_pbt<<<NN, 256, 0, stream>>>(pb, pbt);
  k_cvtall<<<12288, 256, 0, stream>>>(Wq, Wk, Wv, Wo, W1, W2, wall);
  k_decomp<<<1024, 256, 0, stream>>>(x, wc, Tbuf, Sbuf);
  k_tout<<<1024, 256, 0, stream>>>(Tbuf, tw, tb, toutb);
  k_ln<<<MM, 256, 0, stream>>>(Sbuf, ln1g, ln1b, sn);
  k_gemm<0,128><<<dim3(24, 32), 256, 0, stream>>>(sn, wqkvb, DD, b3, nullptr, nullptr, nullptr, qkv);
  k_attn<<<BB * HH * (NN / 128), 512, 0, stream>>>(qkv, qkv + BHND, qkv + 2 * BHND, pbt, obuf);
  k_gemm<1,64><<<dim3(16, 32), 256, 0, stream>>>(obuf, wob, DD, bo, Sbuf, nullptr, xs, nullptr);
  k_ln<<<MM, 256, 0, stream>>>(xs, ln2g, ln2b, hb);
  k_gemm<2,128><<<dim3(32, 32), 256, 0, stream>>>(hb, w1b, DD, b1, nullptr, nullptr, nullptr, gb);
  k_gemm<3,64><<<dim3(16, 32), 256, 0, stream>>>(gb, w2b, HID_, b2, xs, toutb, out, nullptr);
  k_tail<<<1, 1, 0, stream>>>(out);
}